// Round 1
// 745.549 us; speedup vs baseline: 1.8049x; 1.8049x over previous
//
#include <hip/hip_runtime.h>
#include <hip/hip_bf16.h>

// ---------------------------------------------------------------------------
// HetergatWOConcatFeat — round 3: MFMA bf16 GEMMs (was pure-VALU fp32 SGEMM).
//  - gemm_mfma: 128x64 tile, BK=64, 4 waves, v_mfma_f32_16x16x32_bf16,
//    XOR-swizzled LDS (conflict-free ds_read_b128).
//  - hp layout changed [H][N][64] -> [N][H*64]: one GEMM per layer (Nc=512),
//    contiguous per-node gathers in aggregate.
// ---------------------------------------------------------------------------

typedef __hip_bfloat16 bf16;
typedef __attribute__((ext_vector_type(8))) short short8;
typedef __attribute__((ext_vector_type(4))) float f32x4;

__device__ __forceinline__ float bf2f(bf16 v) { return __bfloat162float(v); }
__device__ __forceinline__ float ldin(const void* p, long i, int f32) {
  return f32 ? ((const float*)p)[i] : bf2f(((const bf16*)p)[i]);
}
__device__ __forceinline__ short f2bfbits(float f) {
  bf16 h = __float2bfloat16(f);
  return *reinterpret_cast<short*>(&h);
}
__device__ __forceinline__ float bfbits2f(short b) {
  unsigned u = ((unsigned)(unsigned short)b) << 16;
  return __uint_as_float(u);
}

// Detect input dtype: read first 2048 elements of hemb0 as bf16. If the data
// is really f32, the mantissa halves decode to huge/NaN values.
__global__ __launch_bounds__(64) void detect_kernel(const void* __restrict__ x,
                                                    int* __restrict__ flag) {
  int tid = threadIdx.x;
  float m = 0.f;
  for (int i = tid; i < 2048; i += 64) {
    float v = fabsf(bf2f(((const bf16*)x)[i]));
    if (!(v <= 1e3f)) v = 1e9f;  // NaN/Inf/big -> force detect
    m = fmaxf(m, v);
  }
#pragma unroll
  for (int off = 32; off; off >>= 1) m = fmaxf(m, __shfl_xor(m, off));
  if (tid == 0) flag[0] = (m > 1e3f) ? 1 : 0;
}

// ---------------------------------------------------------------------------
// MFMA GEMM: C[M][Nc] (bf16, row-major) = A[M][K] @ B[K][Nc], fp32 accum.
// amode: 0 = A is ws bf16 row-major; 1 = A is an input tensor (dtype by flag).
// bmode: 0 = B row-major [K][Nc] input; 1 = B head-blocked [H][K][64] input
//        (col -> head col>>6, inner col&63), head stride K*64.
// Tile: BM=128, BN=64, BK=64. 256 threads = 4 waves; wave w owns rows
// [w*32, w*32+32) of the tile, all 64 cols. 16x16x32 bf16 MFMA.
// LDS: As[row][k], Bs[col][k] (B transposed during staging), both with the
// XOR swizzle byte ^= ((row&7)<<4) on 128-B rows -> conflict-free b128 ops.
// ---------------------------------------------------------------------------
#define GBM 128
#define GBN 64
#define GBK 64

__device__ __forceinline__ int swz(int row, int kbyte) {
  return row * 128 + (kbyte ^ ((row & 7) << 4));
}

__global__ __launch_bounds__(256) void gemm_mfma(const void* __restrict__ A, int amode,
                                                 const void* __restrict__ B, int bmode,
                                                 bf16* __restrict__ C,
                                                 int M, int K, int Nc,
                                                 const int* __restrict__ flag) {
  __shared__ bf16 As[GBM * GBK];
  __shared__ bf16 Bs[GBN * GBK];
  const int f32 = flag[0];
  const int af32 = (amode == 1) ? f32 : 0;
  const int m0 = blockIdx.x * GBM;
  const int n0 = blockIdx.y * GBN;
  const int tid = threadIdx.x;
  const int lane = tid & 63;
  const int wrow = (tid >> 6) * 32;

  f32x4 acc[2][4];
#pragma unroll
  for (int m = 0; m < 2; m++)
#pragma unroll
    for (int n = 0; n < 4; n++)
#pragma unroll
      for (int r = 0; r < 4; r++) acc[m][n][r] = 0.f;

  for (int kt = 0; kt < K; kt += GBK) {
    // ---- stage A: 128 rows x 64 k (bf16), 1024 16B slots, 4 per thread ----
#pragma unroll
    for (int j = 0; j < 4; j++) {
      int idx = tid + j * 256;       // 0..1023
      int row = idx >> 3;            // 0..127
      int ks = idx & 7;              // 16B slot within row
      int gm = m0 + row;
      short8 v;
#pragma unroll
      for (int e = 0; e < 8; e++) v[e] = 0;
      if (gm < M) {
        long base = (long)gm * K + kt + ks * 8;
        if (!af32) {
          v = *(const short8*)((const bf16*)A + base);
        } else {
          const float* Af = (const float*)A + base;
#pragma unroll
          for (int e = 0; e < 8; e++) v[e] = f2bfbits(Af[e]);
        }
      }
      *(short8*)((char*)As + swz(row, ks * 16)) = v;
    }
    // ---- stage B transposed: Bs[col][k], 64 cols x 64 k ----
    {
      int n = tid & 63;
      int ks0 = tid >> 6;  // 0..3
#pragma unroll
      for (int jj = 0; jj < 2; jj++) {
        int ks = ks0 + jj * 4;     // 0..7
        int k = kt + ks * 8;
        int col = n0 + n;
        long base;
        int cstr;
        if (bmode == 0) { base = (long)k * Nc + col; cstr = Nc; }
        else { base = ((long)(col >> 6) * K + k) * 64 + (col & 63); cstr = 64; }
        short8 v;
        if (f32) {
          const float* Bf = (const float*)B;
#pragma unroll
          for (int e = 0; e < 8; e++) v[e] = f2bfbits(Bf[base + (long)e * cstr]);
        } else {
          const bf16* Bh = (const bf16*)B;
#pragma unroll
          for (int e = 0; e < 8; e++) v[e] = *(const short*)&Bh[base + (long)e * cstr];
        }
        *(short8*)((char*)Bs + swz(n, ks * 16)) = v;
      }
    }
    __syncthreads();
    // ---- compute: 2 k-halves of 32, per wave 2x4 fragments ----
#pragma unroll
    for (int kh = 0; kh < 2; kh++) {
      int klane = kh * 64 + ((lane >> 4) << 4);  // byte offset of k within row
      short8 af[2], bfr[4];
#pragma unroll
      for (int m = 0; m < 2; m++) {
        int row = wrow + m * 16 + (lane & 15);
        af[m] = *(const short8*)((const char*)As + swz(row, klane));
      }
#pragma unroll
      for (int n = 0; n < 4; n++) {
        int col = n * 16 + (lane & 15);
        bfr[n] = *(const short8*)((const char*)Bs + swz(col, klane));
      }
#pragma unroll
      for (int m = 0; m < 2; m++)
#pragma unroll
        for (int n = 0; n < 4; n++)
          acc[m][n] = __builtin_amdgcn_mfma_f32_16x16x32_bf16(af[m], bfr[n], acc[m][n], 0, 0, 0);
    }
    __syncthreads();
  }
  // ---- C write: row = (lane>>4)*4 + reg, col = lane&15 (verified layout) ----
#pragma unroll
  for (int m = 0; m < 2; m++) {
#pragma unroll
    for (int r = 0; r < 4; r++) {
      int row = m0 + wrow + m * 16 + ((lane >> 4) << 2) + r;
      if (row < M) {
#pragma unroll
        for (int n = 0; n < 4; n++) {
          int col = n0 + n * 16 + (lane & 15);
          C[(long)row * Nc + col] = __float2bfloat16(acc[m][n][r]);
        }
      }
    }
  }
}

// s[n,h] = hp[n,h,:]·asrc[h,:] ; t[n,h] = hp[n,h,:]·atrg[h,:]
// hp layout: [N][H*64] bf16.
__global__ __launch_bounds__(256) void st_kernel(const bf16* __restrict__ hp,
                                                 const void* __restrict__ asrc,
                                                 const void* __restrict__ atrg,
                                                 float* __restrict__ sv,
                                                 float* __restrict__ tv, int N,
                                                 const int* __restrict__ flag) {
  const int f32 = flag[0];
  int i = blockIdx.x * 256 + threadIdx.x;
  if (i >= N * 8) return;
  int h = i / N;
  int n = i - h * N;
  const bf16* hpp = hp + (long)n * 512 + h * 64;
  float s = 0.f, t = 0.f;
#pragma unroll
  for (int c = 0; c < 8; c++) {
    short8 v = *(const short8*)(hpp + c * 8);
#pragma unroll
    for (int e = 0; e < 8; e++) {
      float x = bfbits2f(v[e]);
      int o = c * 8 + e;
      s += x * ldin(asrc, h * 64 + o, f32);
      t += x * ldin(atrg, h * 64 + o, f32);
    }
  }
  sv[n * 8 + h] = s;
  tv[n * 8 + h] = t;
}

// ---- CSR build ----
__global__ void hist_kernel(const int* __restrict__ trg, int* __restrict__ deg, int E) {
  int e = blockIdx.x * 256 + threadIdx.x;
  if (e < E) atomicAdd(&deg[trg[e]], 1);
}

__global__ __launch_bounds__(1024) void scan_kernel(const int* __restrict__ deg,
                                                    int* __restrict__ row_ptr,
                                                    int* __restrict__ fil, int N) {
  __shared__ int sums[1024];
  int tid = threadIdx.x;
  int chunk = (N + 1023) >> 10;
  int start = tid * chunk;
  int end = start + chunk;
  if (start > N) start = N;
  if (end > N) end = N;
  int s = 0;
  for (int i = start; i < end; i++) s += deg[i];
  sums[tid] = s;
  __syncthreads();
  for (int off = 1; off < 1024; off <<= 1) {
    int add = (tid >= off) ? sums[tid - off] : 0;
    __syncthreads();
    sums[tid] += add;
    __syncthreads();
  }
  int run = (tid > 0) ? sums[tid - 1] : 0;
  for (int i = start; i < end; i++) {
    row_ptr[i] = run;
    fil[i] = run;
    run += deg[i];
  }
  if (tid == 0) row_ptr[N] = sums[1023];
}

__global__ void fill_kernel(const int* __restrict__ src, const int* __restrict__ trg,
                            int* __restrict__ fil, int* __restrict__ col, int E) {
  int e = blockIdx.x * 256 + threadIdx.x;
  if (e >= E) return;
  int t = trg[e];
  int pos = atomicAdd(&fil[t], 1);
  col[pos] = src[e];
}

// GAT aggregation (gather form). One block per target node. hp: [N][H*64].
// mode 0: bf16 out[n*512 + h*64 + o] = elu(sum)
// mode 1: float out[n*128 + o] = mean_h(sum)   (caller offsets out by type slot)
#define CAP 128
__global__ __launch_bounds__(256) void aggregate(const bf16* __restrict__ hp,
                                                 const float* __restrict__ sv,
                                                 const float* __restrict__ tv,
                                                 const int* __restrict__ row_ptr,
                                                 const int* __restrict__ col_src,
                                                 void* __restrict__ out, int N, int mode) {
  int n = blockIdx.x;
  int tid = threadIdx.x;
  __shared__ float s_denom[8];
  __shared__ float s_ex[CAP * 8];
  __shared__ int s_src[CAP];
  __shared__ float s_red[512];
  int start = row_ptr[n], end = row_ptr[n + 1];
  int deg = end - start;
  if (tid < 8) s_denom[tid] = 0.f;
  __syncthreads();
  for (int i = tid; i < deg * 8; i += 256) {
    int e = i >> 3, h = i & 7;
    int sidx = col_src[start + e];
    float v = sv[sidx * 8 + h] + tv[n * 8 + h];
    v = v > 0.f ? v : 0.2f * v;
    float ex = __expf(v);
    atomicAdd(&s_denom[h], ex);
    if (e < CAP) {
      s_ex[e * 8 + h] = ex;
      if (h == 0) s_src[e] = sidx;
    }
  }
  __syncthreads();
  int h = tid >> 5, ol = tid & 31;
  float dinv = 1.f / (s_denom[h] + 1e-16f);
  float acc0 = 0.f, acc1 = 0.f;
  for (int e = 0; e < deg; e++) {
    int sidx;
    float ex;
    if (e < CAP) {
      sidx = s_src[e];
      ex = s_ex[e * 8 + h];
    } else {
      sidx = col_src[start + e];
      float v = sv[sidx * 8 + h] + tv[n * 8 + h];
      v = v > 0.f ? v : 0.2f * v;
      ex = __expf(v);
    }
    float a = ex * dinv;
    const bf16* hpp = hp + (long)sidx * 512 + h * 64;
    acc0 += a * bf2f(hpp[ol]);
    acc1 += a * bf2f(hpp[ol + 32]);
  }
  if (mode == 0) {
    float e0 = acc0 > 0.f ? acc0 : expm1f(acc0);
    float e1 = acc1 > 0.f ? acc1 : expm1f(acc1);
    bf16* o16 = (bf16*)out;
    o16[(long)n * 512 + h * 64 + ol] = __float2bfloat16(e0);
    o16[(long)n * 512 + h * 64 + ol + 32] = __float2bfloat16(e1);
  } else {
    s_red[h * 64 + ol] = acc0;
    s_red[h * 64 + ol + 32] = acc1;
    __syncthreads();
    if (tid < 64) {
      float sum = 0.f;
#pragma unroll
      for (int hh = 0; hh < 8; hh++) sum += s_red[hh * 64 + tid];
      ((float*)out)[(long)n * 128 + tid] = sum * 0.125f;
    }
  }
}

// favec[o] = trans1[0,:]·aw1[:,o]
__global__ __launch_bounds__(64) void favec_kernel(const bf16* __restrict__ trans1,
                                                   const void* __restrict__ aw1,
                                                   float* __restrict__ favec,
                                                   const int* __restrict__ flag) {
  const int f32 = flag[0];
  int o = threadIdx.x;
  float acc = 0.f;
  for (int k = 0; k < 256; k++) acc += bf2f(trans1[k]) * ldin(aw1, k * 64 + o, f32);
  favec[o] = acc;
}

// Semantic attention + FC + log_softmax. One wave per node.
__global__ __launch_bounds__(64) void final_kernel(const float* __restrict__ ta,
                                                   const float* __restrict__ favec,
                                                   const void* __restrict__ aw2,
                                                   const void* __restrict__ am,
                                                   const void* __restrict__ fcw,
                                                   const void* __restrict__ fcb,
                                                   void* __restrict__ out, int N,
                                                   const int* __restrict__ flag) {
  const int f32 = flag[0];
  int n = blockIdx.x;
  int o = threadIdx.x;
  __shared__ float s0[64], s1[64];
  float ta0 = ta[(long)n * 128 + o];
  float ta1 = ta[(long)n * 128 + 64 + o];
  s0[o] = ta0;
  s1[o] = ta1;
  __syncthreads();
  float f = favec[o];
  float acc0 = f, acc1 = f;
  for (int k = 0; k < 64; k++) {
    float w = ldin(aw2, k * 64 + o, f32);
    acc0 += s0[k] * w;
    acc1 += s1[k] * w;
  }
  float amv = ldin(am, o, f32);
  float p0 = tanhf(acc0) * amv;
  float p1 = tanhf(acc1) * amv;
#pragma unroll
  for (int off = 32; off > 0; off >>= 1) {
    p0 += __shfl_xor(p0, off);
    p1 += __shfl_xor(p1, off);
  }
  float mx = fmaxf(p0, p1);
  float e0 = __expf(p0 - mx), e1 = __expf(p1 - mx);
  float b0 = e0 / (e0 + e1), b1 = e1 / (e0 + e1);
  float fus = b0 * ta0 + b1 * ta1;
  float l0 = ta0 * ldin(fcw, o * 2 + 0, f32) + ta1 * ldin(fcw, (64 + o) * 2 + 0, f32) +
             fus * ldin(fcw, (128 + o) * 2 + 0, f32);
  float l1 = ta0 * ldin(fcw, o * 2 + 1, f32) + ta1 * ldin(fcw, (64 + o) * 2 + 1, f32) +
             fus * ldin(fcw, (128 + o) * 2 + 1, f32);
#pragma unroll
  for (int off = 32; off > 0; off >>= 1) {
    l0 += __shfl_xor(l0, off);
    l1 += __shfl_xor(l1, off);
  }
  if (o == 0) {
    l0 += ldin(fcb, 0, f32);
    l1 += ldin(fcb, 1, f32);
    float m2 = fmaxf(l0, l1);
    float lse = m2 + logf(__expf(l0 - m2) + __expf(l1 - m2));
    if (f32) {
      ((float*)out)[n * 2 + 0] = l0 - lse;
      ((float*)out)[n * 2 + 1] = l1 - lse;
    } else {
      ((bf16*)out)[n * 2 + 0] = __float2bfloat16(l0 - lse);
      ((bf16*)out)[n * 2 + 1] = __float2bfloat16(l1 - lse);
    }
  }
}

extern "C" void kernel_launch(void* const* d_in, const int* in_sizes, int n_in,
                              void* d_out, int out_size, void* d_ws, size_t ws_size,
                              hipStream_t stream) {
  constexpr int N = 20000, E = 320000, H = 8, F0 = 128, FU = 256, FO = 64;
  const void* hemb[2] = {d_in[0], d_in[1]};
  const void* W[2] = {d_in[2], d_in[3]};
  const void* gw[2][2] = {{d_in[4], d_in[7]}, {d_in[10], d_in[13]}};
  const void* gasrc[2][2] = {{d_in[5], d_in[8]}, {d_in[11], d_in[14]}};
  const void* gatrg[2][2] = {{d_in[6], d_in[9]}, {d_in[12], d_in[15]}};
  const void* aw1 = d_in[16];
  const void* aw2 = d_in[17];
  const void* am = d_in[18];
  const void* fcw = d_in[19];
  const void* fcb = d_in[20];
  const int* edge[2] = {(const int*)d_in[21], (const int*)d_in[22]};

  char* p = (char*)d_ws;
  auto alloc = [&](size_t bytes) -> void* {
    void* r = (void*)p;
    p += (bytes + 255) & ~(size_t)255;
    return r;
  };
  int* flag = (int*)alloc(4);
  bf16* trans = (bf16*)alloc((size_t)N * FU * 2);        // 10.24 MB
  bf16* hp = (bf16*)alloc((size_t)N * H * FO * 2);       // 20.48 MB  [N][512]
  bf16* xbuf = (bf16*)alloc((size_t)N * H * FO * 2);     // 20.48 MB  [N][512]
  float* sv = (float*)alloc((size_t)N * H * 4);          // 0.64 MB
  float* tv = (float*)alloc((size_t)N * H * 4);          // 0.64 MB
  float* ta = (float*)alloc((size_t)N * 2 * FO * 4);     // 10.24 MB
  float* favec = (float*)alloc(FO * 4);
  int* deg[2];
  int* rp[2];
  int* fil[2];
  int* col[2];
  for (int t = 0; t < 2; t++) {
    deg[t] = (int*)alloc((size_t)N * 4);
    rp[t] = (int*)alloc((size_t)(N + 1) * 4);
    fil[t] = (int*)alloc((size_t)N * 4);
    col[t] = (int*)alloc((size_t)E * 4);
  }

  detect_kernel<<<1, 64, 0, stream>>>(hemb[0], flag);

  for (int t = 0; t < 2; t++) {
    hipMemsetAsync(deg[t], 0, (size_t)N * 4, stream);
    hist_kernel<<<(E + 255) / 256, 256, 0, stream>>>(edge[t] + E, deg[t], E);
    scan_kernel<<<1, 1024, 0, stream>>>(deg[t], rp[t], fil[t], N);
    fill_kernel<<<(E + 255) / 256, 256, 0, stream>>>(edge[t], edge[t] + E, fil[t], col[t], E);
  }

  const int gmx = (N + GBM - 1) / GBM;  // 157

  for (int t = 0; t < 2; t++) {
    // trans = hemb @ W  [N, FU] (bf16 ws); A dynamic input, B row-major input
    gemm_mfma<<<dim3(gmx, FU / GBN), 256, 0, stream>>>(hemb[t], 1, W[t], 0, trans,
                                                       N, F0, FU, flag);
    // hp[n][h*64+o] layer 0: single GEMM, Nc=512, B head-blocked [H][FU][64]
    gemm_mfma<<<dim3(gmx, (H * FO) / GBN), 256, 0, stream>>>(trans, 0, gw[t][0], 1, hp,
                                                             N, FU, H * FO, flag);
    st_kernel<<<(N * H + 255) / 256, 256, 0, stream>>>(hp, gasrc[t][0], gatrg[t][0], sv, tv, N, flag);
    aggregate<<<N, 256, 0, stream>>>(hp, sv, tv, rp[t], col[t], xbuf, N, 0);
    // hp layer 1 (input xbuf [N, 512]): Nc=512, K=512, B head-blocked [H][512][64]
    gemm_mfma<<<dim3(gmx, (H * FO) / GBN), 256, 0, stream>>>(xbuf, 0, gw[t][1], 1, hp,
                                                             N, H * FO, H * FO, flag);
    st_kernel<<<(N * H + 255) / 256, 256, 0, stream>>>(hp, gasrc[t][1], gatrg[t][1], sv, tv, N, flag);
    aggregate<<<N, 256, 0, stream>>>(hp, sv, tv, rp[t], col[t], ta + t * FO, N, 1);
  }

  favec_kernel<<<1, 64, 0, stream>>>(trans, aw1, favec, flag);
  final_kernel<<<N, 64, 0, stream>>>(ta, favec, aw2, am, fcw, fcb, d_out, N, flag);
}

// Round 2
// 690.757 us; speedup vs baseline: 1.9481x; 1.0793x over previous
//
#include <hip/hip_runtime.h>
#include <hip/hip_bf16.h>

// ---------------------------------------------------------------------------
// HetergatWOConcatFeat — round 4: vectorized, pipelined aggregate gather.
//  - aggregate: 4 edge-groups x 64 lanes; one coalesced 1KB row load per edge
//    (global_load_dwordx4 per lane), 2-deep pipeline -> 8 x 16B loads in
//    flight per block (was: serial scalar 2B loads, VGPR=12, latency-bound).
//  - LDS cross-group reduce with conflict-free [g][j*64+c] layout.
//  - GEMMs unchanged from round 3 (MFMA bf16, swizzled LDS).
// ---------------------------------------------------------------------------

typedef __hip_bfloat16 bf16;
typedef __attribute__((ext_vector_type(8))) short short8;
typedef __attribute__((ext_vector_type(4))) float f32x4;

__device__ __forceinline__ float bf2f(bf16 v) { return __bfloat162float(v); }
__device__ __forceinline__ float ldin(const void* p, long i, int f32) {
  return f32 ? ((const float*)p)[i] : bf2f(((const bf16*)p)[i]);
}
__device__ __forceinline__ short f2bfbits(float f) {
  bf16 h = __float2bfloat16(f);
  return *reinterpret_cast<short*>(&h);
}
__device__ __forceinline__ float bfbits2f(short b) {
  unsigned u = ((unsigned)(unsigned short)b) << 16;
  return __uint_as_float(u);
}

// Detect input dtype: read first 2048 elements of hemb0 as bf16. If the data
// is really f32, the mantissa halves decode to huge/NaN values.
__global__ __launch_bounds__(64) void detect_kernel(const void* __restrict__ x,
                                                    int* __restrict__ flag) {
  int tid = threadIdx.x;
  float m = 0.f;
  for (int i = tid; i < 2048; i += 64) {
    float v = fabsf(bf2f(((const bf16*)x)[i]));
    if (!(v <= 1e3f)) v = 1e9f;  // NaN/Inf/big -> force detect
    m = fmaxf(m, v);
  }
#pragma unroll
  for (int off = 32; off; off >>= 1) m = fmaxf(m, __shfl_xor(m, off));
  if (tid == 0) flag[0] = (m > 1e3f) ? 1 : 0;
}

// ---------------------------------------------------------------------------
// MFMA GEMM: C[M][Nc] (bf16, row-major) = A[M][K] @ B[K][Nc], fp32 accum.
// amode: 0 = A is ws bf16 row-major; 1 = A is an input tensor (dtype by flag).
// bmode: 0 = B row-major [K][Nc] input; 1 = B head-blocked [H][K][64] input.
// Tile: BM=128, BN=64, BK=64. 256 threads = 4 waves. 16x16x32 bf16 MFMA.
// LDS: As[row][k], Bs[col][k] (B transposed), XOR swizzle -> conflict-free.
// ---------------------------------------------------------------------------
#define GBM 128
#define GBN 64
#define GBK 64

__device__ __forceinline__ int swz(int row, int kbyte) {
  return row * 128 + (kbyte ^ ((row & 7) << 4));
}

__global__ __launch_bounds__(256) void gemm_mfma(const void* __restrict__ A, int amode,
                                                 const void* __restrict__ B, int bmode,
                                                 bf16* __restrict__ C,
                                                 int M, int K, int Nc,
                                                 const int* __restrict__ flag) {
  __shared__ bf16 As[GBM * GBK];
  __shared__ bf16 Bs[GBN * GBK];
  const int f32 = flag[0];
  const int af32 = (amode == 1) ? f32 : 0;
  const int m0 = blockIdx.x * GBM;
  const int n0 = blockIdx.y * GBN;
  const int tid = threadIdx.x;
  const int lane = tid & 63;
  const int wrow = (tid >> 6) * 32;

  f32x4 acc[2][4];
#pragma unroll
  for (int m = 0; m < 2; m++)
#pragma unroll
    for (int n = 0; n < 4; n++)
#pragma unroll
      for (int r = 0; r < 4; r++) acc[m][n][r] = 0.f;

  for (int kt = 0; kt < K; kt += GBK) {
    // ---- stage A: 128 rows x 64 k (bf16), 1024 16B slots, 4 per thread ----
#pragma unroll
    for (int j = 0; j < 4; j++) {
      int idx = tid + j * 256;       // 0..1023
      int row = idx >> 3;            // 0..127
      int ks = idx & 7;              // 16B slot within row
      int gm = m0 + row;
      short8 v;
#pragma unroll
      for (int e = 0; e < 8; e++) v[e] = 0;
      if (gm < M) {
        long base = (long)gm * K + kt + ks * 8;
        if (!af32) {
          v = *(const short8*)((const bf16*)A + base);
        } else {
          const float* Af = (const float*)A + base;
#pragma unroll
          for (int e = 0; e < 8; e++) v[e] = f2bfbits(Af[e]);
        }
      }
      *(short8*)((char*)As + swz(row, ks * 16)) = v;
    }
    // ---- stage B transposed: Bs[col][k], 64 cols x 64 k ----
    {
      int n = tid & 63;
      int ks0 = tid >> 6;  // 0..3
#pragma unroll
      for (int jj = 0; jj < 2; jj++) {
        int ks = ks0 + jj * 4;     // 0..7
        int k = kt + ks * 8;
        int col = n0 + n;
        long base;
        int cstr;
        if (bmode == 0) { base = (long)k * Nc + col; cstr = Nc; }
        else { base = ((long)(col >> 6) * K + k) * 64 + (col & 63); cstr = 64; }
        short8 v;
        if (f32) {
          const float* Bf = (const float*)B;
#pragma unroll
          for (int e = 0; e < 8; e++) v[e] = f2bfbits(Bf[base + (long)e * cstr]);
        } else {
          const bf16* Bh = (const bf16*)B;
#pragma unroll
          for (int e = 0; e < 8; e++) v[e] = *(const short*)&Bh[base + (long)e * cstr];
        }
        *(short8*)((char*)Bs + swz(n, ks * 16)) = v;
      }
    }
    __syncthreads();
    // ---- compute: 2 k-halves of 32, per wave 2x4 fragments ----
#pragma unroll
    for (int kh = 0; kh < 2; kh++) {
      int klane = kh * 64 + ((lane >> 4) << 4);  // byte offset of k within row
      short8 af[2], bfr[4];
#pragma unroll
      for (int m = 0; m < 2; m++) {
        int row = wrow + m * 16 + (lane & 15);
        af[m] = *(const short8*)((const char*)As + swz(row, klane));
      }
#pragma unroll
      for (int n = 0; n < 4; n++) {
        int col = n * 16 + (lane & 15);
        bfr[n] = *(const short8*)((const char*)Bs + swz(col, klane));
      }
#pragma unroll
      for (int m = 0; m < 2; m++)
#pragma unroll
        for (int n = 0; n < 4; n++)
          acc[m][n] = __builtin_amdgcn_mfma_f32_16x16x32_bf16(af[m], bfr[n], acc[m][n], 0, 0, 0);
    }
    __syncthreads();
  }
  // ---- C write: row = (lane>>4)*4 + reg, col = lane&15 ----
#pragma unroll
  for (int m = 0; m < 2; m++) {
#pragma unroll
    for (int r = 0; r < 4; r++) {
      int row = m0 + wrow + m * 16 + ((lane >> 4) << 2) + r;
      if (row < M) {
#pragma unroll
        for (int n = 0; n < 4; n++) {
          int col = n0 + n * 16 + (lane & 15);
          C[(long)row * Nc + col] = __float2bfloat16(acc[m][n][r]);
        }
      }
    }
  }
}

// s[n,h] = hp[n,h,:]·asrc[h,:] ; t[n,h] = hp[n,h,:]·atrg[h,:]
// hp layout: [N][H*64] bf16.
__global__ __launch_bounds__(256) void st_kernel(const bf16* __restrict__ hp,
                                                 const void* __restrict__ asrc,
                                                 const void* __restrict__ atrg,
                                                 float* __restrict__ sv,
                                                 float* __restrict__ tv, int N,
                                                 const int* __restrict__ flag) {
  const int f32 = flag[0];
  int i = blockIdx.x * 256 + threadIdx.x;
  if (i >= N * 8) return;
  int h = i / N;
  int n = i - h * N;
  const bf16* hpp = hp + (long)n * 512 + h * 64;
  float s = 0.f, t = 0.f;
#pragma unroll
  for (int c = 0; c < 8; c++) {
    short8 v = *(const short8*)(hpp + c * 8);
#pragma unroll
    for (int e = 0; e < 8; e++) {
      float x = bfbits2f(v[e]);
      int o = c * 8 + e;
      s += x * ldin(asrc, h * 64 + o, f32);
      t += x * ldin(atrg, h * 64 + o, f32);
    }
  }
  sv[n * 8 + h] = s;
  tv[n * 8 + h] = t;
}

// ---- CSR build ----
__global__ void hist_kernel(const int* __restrict__ trg, int* __restrict__ deg, int E) {
  int e = blockIdx.x * 256 + threadIdx.x;
  if (e < E) atomicAdd(&deg[trg[e]], 1);
}

__global__ __launch_bounds__(1024) void scan_kernel(const int* __restrict__ deg,
                                                    int* __restrict__ row_ptr,
                                                    int* __restrict__ fil, int N) {
  __shared__ int sums[1024];
  int tid = threadIdx.x;
  int chunk = (N + 1023) >> 10;
  int start = tid * chunk;
  int end = start + chunk;
  if (start > N) start = N;
  if (end > N) end = N;
  int s = 0;
  for (int i = start; i < end; i++) s += deg[i];
  sums[tid] = s;
  __syncthreads();
  for (int off = 1; off < 1024; off <<= 1) {
    int add = (tid >= off) ? sums[tid - off] : 0;
    __syncthreads();
    sums[tid] += add;
    __syncthreads();
  }
  int run = (tid > 0) ? sums[tid - 1] : 0;
  for (int i = start; i < end; i++) {
    row_ptr[i] = run;
    fil[i] = run;
    run += deg[i];
  }
  if (tid == 0) row_ptr[N] = sums[1023];
}

__global__ void fill_kernel(const int* __restrict__ src, const int* __restrict__ trg,
                            int* __restrict__ fil, int* __restrict__ col, int E) {
  int e = blockIdx.x * 256 + threadIdx.x;
  if (e >= E) return;
  int t = trg[e];
  int pos = atomicAdd(&fil[t], 1);
  col[pos] = src[e];
}

// ---------------------------------------------------------------------------
// GAT aggregation (gather form). One block per target node. hp: [N][H*64].
// 4 edge-groups (g = tid>>6) x 64 lanes (c = tid&63, a 16B column of the 1KB
// row). Per edge one wave issues a single coalesced 1KB load (dwordx4/lane);
// 2 edges per group in flight (2-deep pipeline) -> 8 independent 16B loads
// outstanding per block. Cross-group LDS reduce, layout [g][j*64+c]
// (conflict-free stores).
// mode 0: bf16 out[n*512 + o] = elu(sum)
// mode 1: float out[n*128 + o] = mean_h(sum)   (caller offsets out by slot)
// ---------------------------------------------------------------------------
#define CAP 128
__global__ __launch_bounds__(256) void aggregate(const bf16* __restrict__ hp,
                                                 const float* __restrict__ sv,
                                                 const float* __restrict__ tv,
                                                 const int* __restrict__ row_ptr,
                                                 const int* __restrict__ col_src,
                                                 void* __restrict__ out, int N, int mode) {
  int n = blockIdx.x;
  int tid = threadIdx.x;
  __shared__ float s_denom[8];
  __shared__ float s_tv[8];
  __shared__ float s_ex[CAP * 8];
  __shared__ int s_src[CAP];
  __shared__ float s_red[4 * 512];
  int start = row_ptr[n], end = row_ptr[n + 1];
  int deg = end - start;
  if (tid < 8) {
    s_denom[tid] = 0.f;
    s_tv[tid] = tv[(long)n * 8 + tid];
  }
  __syncthreads();
  // phase 1: ex for cached edges + denom (full-degree)
  for (int i = tid; i < deg * 8; i += 256) {
    int e = i >> 3, h = i & 7;
    int sidx = col_src[start + e];
    float v = sv[sidx * 8 + h] + s_tv[h];
    v = v > 0.f ? v : 0.2f * v;
    float ex = __expf(v);
    atomicAdd(&s_denom[h], ex);
    if (e < CAP) {
      s_ex[e * 8 + h] = ex;
      if (h == 0) s_src[e] = sidx;
    }
  }
  __syncthreads();
  const int g = tid >> 6;   // edge group, wave-uniform
  const int c = tid & 63;   // 16B column of the 1KB row
  const int h = c >> 3;
  const float dinv = 1.f / (s_denom[h] + 1e-16f);
  const int degc = deg < CAP ? deg : CAP;
  float acc[8] = {0.f, 0.f, 0.f, 0.f, 0.f, 0.f, 0.f, 0.f};
  const bf16* __restrict__ hpc = hp + c * 8;
  // main loop: 2 edges per iteration per group (2-deep pipeline)
  for (int e = g; e < degc; e += 8) {
    int e1 = e + 4;
    int has2 = (e1 < degc);
    int s0 = s_src[e];
    int s1 = has2 ? s_src[e1] : s0;
    short8 v0 = *(const short8*)(hpc + (long)s0 * 512);
    short8 v1 = *(const short8*)(hpc + (long)s1 * 512);
    float a0 = s_ex[e * 8 + h] * dinv;
    float a1 = has2 ? s_ex[e1 * 8 + h] * dinv : 0.f;
#pragma unroll
    for (int j = 0; j < 8; j++) acc[j] += a0 * bfbits2f(v0[j]);
#pragma unroll
    for (int j = 0; j < 8; j++) acc[j] += a1 * bfbits2f(v1[j]);
  }
  // rare tail: deg > CAP (recompute ex)
  for (int e = CAP + g; e < deg; e += 4) {
    int sidx = col_src[start + e];
    float v = sv[sidx * 8 + h] + s_tv[h];
    v = v > 0.f ? v : 0.2f * v;
    float a = __expf(v) * dinv;
    short8 vv = *(const short8*)(hpc + (long)sidx * 512);
#pragma unroll
    for (int j = 0; j < 8; j++) acc[j] += a * bfbits2f(vv[j]);
  }
  // cross-group reduce; store layout [g][j*64 + c]: conflict-free
#pragma unroll
  for (int j = 0; j < 8; j++) s_red[g * 512 + j * 64 + c] = acc[j];
  __syncthreads();
  if (mode == 0) {
    bf16* o16 = (bf16*)out + (long)n * 512;
    unsigned pak = 0;
#pragma unroll
    for (int j = 0; j < 2; j++) {
      int o = tid * 2 + j;                    // output element o = col*8 + slot
      int addr = (o & 7) * 64 + (o >> 3);
      float s = s_red[addr] + s_red[512 + addr] + s_red[1024 + addr] + s_red[1536 + addr];
      float ev = s > 0.f ? s : expm1f(s);
      pak |= ((unsigned)(unsigned short)f2bfbits(ev)) << (16 * j);
    }
    *(unsigned*)(o16 + tid * 2) = pak;
  } else {
    if (tid < 64) {
      float s = 0.f;
#pragma unroll
      for (int hh = 0; hh < 8; hh++) {
        int o = hh * 64 + tid;
        int addr = (o & 7) * 64 + (o >> 3);
        s += s_red[addr] + s_red[512 + addr] + s_red[1024 + addr] + s_red[1536 + addr];
      }
      ((float*)out)[(long)n * 128 + tid] = s * 0.125f;
    }
  }
}

// favec[o] = trans1[0,:]·aw1[:,o]
__global__ __launch_bounds__(64) void favec_kernel(const bf16* __restrict__ trans1,
                                                   const void* __restrict__ aw1,
                                                   float* __restrict__ favec,
                                                   const int* __restrict__ flag) {
  const int f32 = flag[0];
  int o = threadIdx.x;
  float acc = 0.f;
  for (int k = 0; k < 256; k++) acc += bf2f(trans1[k]) * ldin(aw1, k * 64 + o, f32);
  favec[o] = acc;
}

// Semantic attention + FC + log_softmax. One wave per node.
__global__ __launch_bounds__(64) void final_kernel(const float* __restrict__ ta,
                                                   const float* __restrict__ favec,
                                                   const void* __restrict__ aw2,
                                                   const void* __restrict__ am,
                                                   const void* __restrict__ fcw,
                                                   const void* __restrict__ fcb,
                                                   void* __restrict__ out, int N,
                                                   const int* __restrict__ flag) {
  const int f32 = flag[0];
  int n = blockIdx.x;
  int o = threadIdx.x;
  __shared__ float s0[64], s1[64];
  float ta0 = ta[(long)n * 128 + o];
  float ta1 = ta[(long)n * 128 + 64 + o];
  s0[o] = ta0;
  s1[o] = ta1;
  __syncthreads();
  float f = favec[o];
  float acc0 = f, acc1 = f;
  for (int k = 0; k < 64; k++) {
    float w = ldin(aw2, k * 64 + o, f32);
    acc0 += s0[k] * w;
    acc1 += s1[k] * w;
  }
  float amv = ldin(am, o, f32);
  float p0 = tanhf(acc0) * amv;
  float p1 = tanhf(acc1) * amv;
#pragma unroll
  for (int off = 32; off > 0; off >>= 1) {
    p0 += __shfl_xor(p0, off);
    p1 += __shfl_xor(p1, off);
  }
  float mx = fmaxf(p0, p1);
  float e0 = __expf(p0 - mx), e1 = __expf(p1 - mx);
  float b0 = e0 / (e0 + e1), b1 = e1 / (e0 + e1);
  float fus = b0 * ta0 + b1 * ta1;
  float l0 = ta0 * ldin(fcw, o * 2 + 0, f32) + ta1 * ldin(fcw, (64 + o) * 2 + 0, f32) +
             fus * ldin(fcw, (128 + o) * 2 + 0, f32);
  float l1 = ta0 * ldin(fcw, o * 2 + 1, f32) + ta1 * ldin(fcw, (64 + o) * 2 + 1, f32) +
             fus * ldin(fcw, (128 + o) * 2 + 1, f32);
#pragma unroll
  for (int off = 32; off > 0; off >>= 1) {
    l0 += __shfl_xor(l0, off);
    l1 += __shfl_xor(l1, off);
  }
  if (o == 0) {
    l0 += ldin(fcb, 0, f32);
    l1 += ldin(fcb, 1, f32);
    float m2 = fmaxf(l0, l1);
    float lse = m2 + logf(__expf(l0 - m2) + __expf(l1 - m2));
    if (f32) {
      ((float*)out)[n * 2 + 0] = l0 - lse;
      ((float*)out)[n * 2 + 1] = l1 - lse;
    } else {
      ((bf16*)out)[n * 2 + 0] = __float2bfloat16(l0 - lse);
      ((bf16*)out)[n * 2 + 1] = __float2bfloat16(l1 - lse);
    }
  }
}

extern "C" void kernel_launch(void* const* d_in, const int* in_sizes, int n_in,
                              void* d_out, int out_size, void* d_ws, size_t ws_size,
                              hipStream_t stream) {
  constexpr int N = 20000, E = 320000, H = 8, F0 = 128, FU = 256, FO = 64;
  const void* hemb[2] = {d_in[0], d_in[1]};
  const void* W[2] = {d_in[2], d_in[3]};
  const void* gw[2][2] = {{d_in[4], d_in[7]}, {d_in[10], d_in[13]}};
  const void* gasrc[2][2] = {{d_in[5], d_in[8]}, {d_in[11], d_in[14]}};
  const void* gatrg[2][2] = {{d_in[6], d_in[9]}, {d_in[12], d_in[15]}};
  const void* aw1 = d_in[16];
  const void* aw2 = d_in[17];
  const void* am = d_in[18];
  const void* fcw = d_in[19];
  const void* fcb = d_in[20];
  const int* edge[2] = {(const int*)d_in[21], (const int*)d_in[22]};

  char* p = (char*)d_ws;
  auto alloc = [&](size_t bytes) -> void* {
    void* r = (void*)p;
    p += (bytes + 255) & ~(size_t)255;
    return r;
  };
  int* flag = (int*)alloc(4);
  bf16* trans = (bf16*)alloc((size_t)N * FU * 2);        // 10.24 MB
  bf16* hp = (bf16*)alloc((size_t)N * H * FO * 2);       // 20.48 MB  [N][512]
  bf16* xbuf = (bf16*)alloc((size_t)N * H * FO * 2);     // 20.48 MB  [N][512]
  float* sv = (float*)alloc((size_t)N * H * 4);          // 0.64 MB
  float* tv = (float*)alloc((size_t)N * H * 4);          // 0.64 MB
  float* ta = (float*)alloc((size_t)N * 2 * FO * 4);     // 10.24 MB
  float* favec = (float*)alloc(FO * 4);
  int* deg[2];
  int* rp[2];
  int* fil[2];
  int* col[2];
  for (int t = 0; t < 2; t++) {
    deg[t] = (int*)alloc((size_t)N * 4);
    rp[t] = (int*)alloc((size_t)(N + 1) * 4);
    fil[t] = (int*)alloc((size_t)N * 4);
    col[t] = (int*)alloc((size_t)E * 4);
  }

  detect_kernel<<<1, 64, 0, stream>>>(hemb[0], flag);

  for (int t = 0; t < 2; t++) {
    hipMemsetAsync(deg[t], 0, (size_t)N * 4, stream);
    hist_kernel<<<(E + 255) / 256, 256, 0, stream>>>(edge[t] + E, deg[t], E);
    scan_kernel<<<1, 1024, 0, stream>>>(deg[t], rp[t], fil[t], N);
    fill_kernel<<<(E + 255) / 256, 256, 0, stream>>>(edge[t], edge[t] + E, fil[t], col[t], E);
  }

  const int gmx = (N + GBM - 1) / GBM;  // 157

  for (int t = 0; t < 2; t++) {
    // trans = hemb @ W  [N, FU] (bf16 ws); A dynamic input, B row-major input
    gemm_mfma<<<dim3(gmx, FU / GBN), 256, 0, stream>>>(hemb[t], 1, W[t], 0, trans,
                                                       N, F0, FU, flag);
    // hp[n][h*64+o] layer 0: single GEMM, Nc=512, B head-blocked [H][FU][64]
    gemm_mfma<<<dim3(gmx, (H * FO) / GBN), 256, 0, stream>>>(trans, 0, gw[t][0], 1, hp,
                                                             N, FU, H * FO, flag);
    st_kernel<<<(N * H + 255) / 256, 256, 0, stream>>>(hp, gasrc[t][0], gatrg[t][0], sv, tv, N, flag);
    aggregate<<<N, 256, 0, stream>>>(hp, sv, tv, rp[t], col[t], xbuf, N, 0);
    // hp layer 1 (input xbuf [N, 512]): Nc=512, K=512, B head-blocked [H][512][64]
    gemm_mfma<<<dim3(gmx, (H * FO) / GBN), 256, 0, stream>>>(xbuf, 0, gw[t][1], 1, hp,
                                                             N, H * FO, H * FO, flag);
    st_kernel<<<(N * H + 255) / 256, 256, 0, stream>>>(hp, gasrc[t][1], gatrg[t][1], sv, tv, N, flag);
    aggregate<<<N, 256, 0, stream>>>(hp, sv, tv, rp[t], col[t], ta + t * FO, N, 1);
  }

  favec_kernel<<<1, 64, 0, stream>>>(trans, aw1, favec, flag);
  final_kernel<<<N, 64, 0, stream>>>(ta, favec, aw2, am, fcw, fcb, d_out, N, flag);
}

// Round 3
// 660.820 us; speedup vs baseline: 2.0363x; 1.0453x over previous
//
#include <hip/hip_runtime.h>
#include <hip/hip_bf16.h>

// ---------------------------------------------------------------------------
// HetergatWOConcatFeat — round 5: fused single-pass wave-per-node aggregate.
//  - softmax denom folded into the gather pass (out = Σ ex·row / Σ ex):
//    no phase-1, no barriers, no LDS, no atomics.
//  - one wave per node: lane c owns 16B column c of the 1KB hp row; each edge
//    is ONE coalesced global_load_dwordx4 wave-instruction. Edge srcs staged
//    one-per-lane + __shfl broadcast. 4-deep unroll -> 4 row loads in flight.
//  - head-mean epilogue (mode 1) via 3-step __shfl_xor (stride-8 lanes).
//  - GEMMs unchanged from round 3 (MFMA bf16, swizzled LDS).
// ---------------------------------------------------------------------------

typedef __hip_bfloat16 bf16;
typedef __attribute__((ext_vector_type(8))) short short8;
typedef __attribute__((ext_vector_type(4))) float f32x4;

__device__ __forceinline__ float bf2f(bf16 v) { return __bfloat162float(v); }
__device__ __forceinline__ float ldin(const void* p, long i, int f32) {
  return f32 ? ((const float*)p)[i] : bf2f(((const bf16*)p)[i]);
}
__device__ __forceinline__ short f2bfbits(float f) {
  bf16 h = __float2bfloat16(f);
  return *reinterpret_cast<short*>(&h);
}
__device__ __forceinline__ float bfbits2f(short b) {
  unsigned u = ((unsigned)(unsigned short)b) << 16;
  return __uint_as_float(u);
}

// Detect input dtype: read first 2048 elements of hemb0 as bf16. If the data
// is really f32, the mantissa halves decode to huge/NaN values.
__global__ __launch_bounds__(64) void detect_kernel(const void* __restrict__ x,
                                                    int* __restrict__ flag) {
  int tid = threadIdx.x;
  float m = 0.f;
  for (int i = tid; i < 2048; i += 64) {
    float v = fabsf(bf2f(((const bf16*)x)[i]));
    if (!(v <= 1e3f)) v = 1e9f;  // NaN/Inf/big -> force detect
    m = fmaxf(m, v);
  }
#pragma unroll
  for (int off = 32; off; off >>= 1) m = fmaxf(m, __shfl_xor(m, off));
  if (tid == 0) flag[0] = (m > 1e3f) ? 1 : 0;
}

// ---------------------------------------------------------------------------
// MFMA GEMM: C[M][Nc] (bf16, row-major) = A[M][K] @ B[K][Nc], fp32 accum.
// amode: 0 = A is ws bf16 row-major; 1 = A is an input tensor (dtype by flag).
// bmode: 0 = B row-major [K][Nc] input; 1 = B head-blocked [H][K][64] input.
// Tile: BM=128, BN=64, BK=64. 256 threads = 4 waves. 16x16x32 bf16 MFMA.
// LDS: As[row][k], Bs[col][k] (B transposed), XOR swizzle -> conflict-free.
// ---------------------------------------------------------------------------
#define GBM 128
#define GBN 64
#define GBK 64

__device__ __forceinline__ int swz(int row, int kbyte) {
  return row * 128 + (kbyte ^ ((row & 7) << 4));
}

__global__ __launch_bounds__(256) void gemm_mfma(const void* __restrict__ A, int amode,
                                                 const void* __restrict__ B, int bmode,
                                                 bf16* __restrict__ C,
                                                 int M, int K, int Nc,
                                                 const int* __restrict__ flag) {
  __shared__ bf16 As[GBM * GBK];
  __shared__ bf16 Bs[GBN * GBK];
  const int f32 = flag[0];
  const int af32 = (amode == 1) ? f32 : 0;
  const int m0 = blockIdx.x * GBM;
  const int n0 = blockIdx.y * GBN;
  const int tid = threadIdx.x;
  const int lane = tid & 63;
  const int wrow = (tid >> 6) * 32;

  f32x4 acc[2][4];
#pragma unroll
  for (int m = 0; m < 2; m++)
#pragma unroll
    for (int n = 0; n < 4; n++)
#pragma unroll
      for (int r = 0; r < 4; r++) acc[m][n][r] = 0.f;

  for (int kt = 0; kt < K; kt += GBK) {
    // ---- stage A: 128 rows x 64 k (bf16), 1024 16B slots, 4 per thread ----
#pragma unroll
    for (int j = 0; j < 4; j++) {
      int idx = tid + j * 256;       // 0..1023
      int row = idx >> 3;            // 0..127
      int ks = idx & 7;              // 16B slot within row
      int gm = m0 + row;
      short8 v;
#pragma unroll
      for (int e = 0; e < 8; e++) v[e] = 0;
      if (gm < M) {
        long base = (long)gm * K + kt + ks * 8;
        if (!af32) {
          v = *(const short8*)((const bf16*)A + base);
        } else {
          const float* Af = (const float*)A + base;
#pragma unroll
          for (int e = 0; e < 8; e++) v[e] = f2bfbits(Af[e]);
        }
      }
      *(short8*)((char*)As + swz(row, ks * 16)) = v;
    }
    // ---- stage B transposed: Bs[col][k], 64 cols x 64 k ----
    {
      int n = tid & 63;
      int ks0 = tid >> 6;  // 0..3
#pragma unroll
      for (int jj = 0; jj < 2; jj++) {
        int ks = ks0 + jj * 4;     // 0..7
        int k = kt + ks * 8;
        int col = n0 + n;
        long base;
        int cstr;
        if (bmode == 0) { base = (long)k * Nc + col; cstr = Nc; }
        else { base = ((long)(col >> 6) * K + k) * 64 + (col & 63); cstr = 64; }
        short8 v;
        if (f32) {
          const float* Bf = (const float*)B;
#pragma unroll
          for (int e = 0; e < 8; e++) v[e] = f2bfbits(Bf[base + (long)e * cstr]);
        } else {
          const bf16* Bh = (const bf16*)B;
#pragma unroll
          for (int e = 0; e < 8; e++) v[e] = *(const short*)&Bh[base + (long)e * cstr];
        }
        *(short8*)((char*)Bs + swz(n, ks * 16)) = v;
      }
    }
    __syncthreads();
    // ---- compute: 2 k-halves of 32, per wave 2x4 fragments ----
#pragma unroll
    for (int kh = 0; kh < 2; kh++) {
      int klane = kh * 64 + ((lane >> 4) << 4);  // byte offset of k within row
      short8 af[2], bfr[4];
#pragma unroll
      for (int m = 0; m < 2; m++) {
        int row = wrow + m * 16 + (lane & 15);
        af[m] = *(const short8*)((const char*)As + swz(row, klane));
      }
#pragma unroll
      for (int n = 0; n < 4; n++) {
        int col = n * 16 + (lane & 15);
        bfr[n] = *(const short8*)((const char*)Bs + swz(col, klane));
      }
#pragma unroll
      for (int m = 0; m < 2; m++)
#pragma unroll
        for (int n = 0; n < 4; n++)
          acc[m][n] = __builtin_amdgcn_mfma_f32_16x16x32_bf16(af[m], bfr[n], acc[m][n], 0, 0, 0);
    }
    __syncthreads();
  }
  // ---- C write: row = (lane>>4)*4 + reg, col = lane&15 ----
#pragma unroll
  for (int m = 0; m < 2; m++) {
#pragma unroll
    for (int r = 0; r < 4; r++) {
      int row = m0 + wrow + m * 16 + ((lane >> 4) << 2) + r;
      if (row < M) {
#pragma unroll
        for (int n = 0; n < 4; n++) {
          int col = n0 + n * 16 + (lane & 15);
          C[(long)row * Nc + col] = __float2bfloat16(acc[m][n][r]);
        }
      }
    }
  }
}

// s[n,h] = hp[n,h,:]·asrc[h,:] ; t[n,h] = hp[n,h,:]·atrg[h,:]
// hp layout: [N][H*64] bf16.
__global__ __launch_bounds__(256) void st_kernel(const bf16* __restrict__ hp,
                                                 const void* __restrict__ asrc,
                                                 const void* __restrict__ atrg,
                                                 float* __restrict__ sv,
                                                 float* __restrict__ tv, int N,
                                                 const int* __restrict__ flag) {
  const int f32 = flag[0];
  int i = blockIdx.x * 256 + threadIdx.x;
  if (i >= N * 8) return;
  int h = i / N;
  int n = i - h * N;
  const bf16* hpp = hp + (long)n * 512 + h * 64;
  float s = 0.f, t = 0.f;
#pragma unroll
  for (int c = 0; c < 8; c++) {
    short8 v = *(const short8*)(hpp + c * 8);
#pragma unroll
    for (int e = 0; e < 8; e++) {
      float x = bfbits2f(v[e]);
      int o = c * 8 + e;
      s += x * ldin(asrc, h * 64 + o, f32);
      t += x * ldin(atrg, h * 64 + o, f32);
    }
  }
  sv[n * 8 + h] = s;
  tv[n * 8 + h] = t;
}

// ---- CSR build ----
__global__ void hist_kernel(const int* __restrict__ trg, int* __restrict__ deg, int E) {
  int e = blockIdx.x * 256 + threadIdx.x;
  if (e < E) atomicAdd(&deg[trg[e]], 1);
}

__global__ __launch_bounds__(1024) void scan_kernel(const int* __restrict__ deg,
                                                    int* __restrict__ row_ptr,
                                                    int* __restrict__ fil, int N) {
  __shared__ int sums[1024];
  int tid = threadIdx.x;
  int chunk = (N + 1023) >> 10;
  int start = tid * chunk;
  int end = start + chunk;
  if (start > N) start = N;
  if (end > N) end = N;
  int s = 0;
  for (int i = start; i < end; i++) s += deg[i];
  sums[tid] = s;
  __syncthreads();
  for (int off = 1; off < 1024; off <<= 1) {
    int add = (tid >= off) ? sums[tid - off] : 0;
    __syncthreads();
    sums[tid] += add;
    __syncthreads();
  }
  int run = (tid > 0) ? sums[tid - 1] : 0;
  for (int i = start; i < end; i++) {
    row_ptr[i] = run;
    fil[i] = run;
    run += deg[i];
  }
  if (tid == 0) row_ptr[N] = sums[1023];
}

__global__ void fill_kernel(const int* __restrict__ src, const int* __restrict__ trg,
                            int* __restrict__ fil, int* __restrict__ col, int E) {
  int e = blockIdx.x * 256 + threadIdx.x;
  if (e >= E) return;
  int t = trg[e];
  int pos = atomicAdd(&fil[t], 1);
  col[pos] = src[e];
}

// ---------------------------------------------------------------------------
// GAT aggregation, fused single pass: out = (Σ_e ex_e · hp[src_e]) / (Σ_e ex_e).
// One wave per node (4 nodes per 256-thread block). Lane c owns bytes
// [c*16, c*16+16) of the 1KB row (head h = c>>3). Per 64-edge chunk the srcs
// are staged one-per-lane and broadcast via __shfl; edges unrolled x4 so 4 row
// loads (dwordx4/lane, fully coalesced) + 4 sv loads are in flight.
// No LDS, no barriers, no atomics. Per-lane redundant per-head denominator.
// mode 0: bf16 out[n*512 + o] = elu(sum)
// mode 1: float out[n*128 + o] = mean_h(sum)  (caller offsets out by slot);
//         head-mean via 3-step __shfl_xor over stride-8 lanes.
// ---------------------------------------------------------------------------
__device__ __forceinline__ float exleaky(float v) {
  v = v > 0.f ? v : 0.2f * v;
  return __expf(v);
}

__global__ __launch_bounds__(256) void aggregate(const bf16* __restrict__ hp,
                                                 const float* __restrict__ sv,
                                                 const float* __restrict__ tv,
                                                 const int* __restrict__ row_ptr,
                                                 const int* __restrict__ col_src,
                                                 void* __restrict__ out, int N, int mode) {
  const int wid = threadIdx.x >> 6;
  const int lane = threadIdx.x & 63;
  const int n = blockIdx.x * 4 + wid;
  if (n >= N) return;
  const int start = row_ptr[n];
  const int deg = row_ptr[n + 1] - start;
  const int h = lane >> 3;
  const float tvh = tv[(long)n * 8 + h];
  const bf16* __restrict__ hpc = hp + lane * 8;

  float acc[8] = {0.f, 0.f, 0.f, 0.f, 0.f, 0.f, 0.f, 0.f};
  float den = 1e-16f;

  for (int base = 0; base < deg; base += 64) {
    int cnt = deg - base;
    if (cnt > 64) cnt = 64;
    int mysrc = (lane < cnt) ? col_src[start + base + lane] : 0;
    int e = 0;
    for (; e + 4 <= cnt; e += 4) {
      int s0 = __shfl(mysrc, e + 0);
      int s1 = __shfl(mysrc, e + 1);
      int s2 = __shfl(mysrc, e + 2);
      int s3 = __shfl(mysrc, e + 3);
      short8 v0 = *(const short8*)(hpc + (long)s0 * 512);
      short8 v1 = *(const short8*)(hpc + (long)s1 * 512);
      short8 v2 = *(const short8*)(hpc + (long)s2 * 512);
      short8 v3 = *(const short8*)(hpc + (long)s3 * 512);
      float a0 = exleaky(sv[(long)s0 * 8 + h] + tvh);
      float a1 = exleaky(sv[(long)s1 * 8 + h] + tvh);
      float a2 = exleaky(sv[(long)s2 * 8 + h] + tvh);
      float a3 = exleaky(sv[(long)s3 * 8 + h] + tvh);
      den += a0 + a1 + a2 + a3;
#pragma unroll
      for (int j = 0; j < 8; j++) acc[j] += a0 * bfbits2f(v0[j]);
#pragma unroll
      for (int j = 0; j < 8; j++) acc[j] += a1 * bfbits2f(v1[j]);
#pragma unroll
      for (int j = 0; j < 8; j++) acc[j] += a2 * bfbits2f(v2[j]);
#pragma unroll
      for (int j = 0; j < 8; j++) acc[j] += a3 * bfbits2f(v3[j]);
    }
    for (; e < cnt; e++) {
      int s0 = __shfl(mysrc, e);
      short8 v0 = *(const short8*)(hpc + (long)s0 * 512);
      float a0 = exleaky(sv[(long)s0 * 8 + h] + tvh);
      den += a0;
#pragma unroll
      for (int j = 0; j < 8; j++) acc[j] += a0 * bfbits2f(v0[j]);
    }
  }

  const float dinv = 1.f / den;
  if (mode == 0) {
    short8 o8;
#pragma unroll
    for (int j = 0; j < 8; j++) {
      float s = acc[j] * dinv;
      float ev = s > 0.f ? s : expm1f(s);
      o8[j] = f2bfbits(ev);
    }
    *(short8*)((bf16*)out + (long)n * 512 + lane * 8) = o8;
  } else {
    float r[8];
#pragma unroll
    for (int j = 0; j < 8; j++) r[j] = acc[j] * dinv;
    // sum across the 8 lanes {q, q+8, ..., q+56} (q = lane&7): heads 0..7
#pragma unroll
    for (int m = 8; m <= 32; m <<= 1)
#pragma unroll
      for (int j = 0; j < 8; j++) r[j] += __shfl_xor(r[j], m);
    if (lane < 8) {
      float* o = (float*)out + (long)n * 128 + lane * 8;
#pragma unroll
      for (int j = 0; j < 8; j++) o[j] = r[j] * 0.125f;
    }
  }
}

// favec[o] = trans1[0,:]·aw1[:,o]
__global__ __launch_bounds__(64) void favec_kernel(const bf16* __restrict__ trans1,
                                                   const void* __restrict__ aw1,
                                                   float* __restrict__ favec,
                                                   const int* __restrict__ flag) {
  const int f32 = flag[0];
  int o = threadIdx.x;
  float acc = 0.f;
  for (int k = 0; k < 256; k++) acc += bf2f(trans1[k]) * ldin(aw1, k * 64 + o, f32);
  favec[o] = acc;
}

// Semantic attention + FC + log_softmax. One wave per node.
__global__ __launch_bounds__(64) void final_kernel(const float* __restrict__ ta,
                                                   const float* __restrict__ favec,
                                                   const void* __restrict__ aw2,
                                                   const void* __restrict__ am,
                                                   const void* __restrict__ fcw,
                                                   const void* __restrict__ fcb,
                                                   void* __restrict__ out, int N,
                                                   const int* __restrict__ flag) {
  const int f32 = flag[0];
  int n = blockIdx.x;
  int o = threadIdx.x;
  __shared__ float s0[64], s1[64];
  float ta0 = ta[(long)n * 128 + o];
  float ta1 = ta[(long)n * 128 + 64 + o];
  s0[o] = ta0;
  s1[o] = ta1;
  __syncthreads();
  float f = favec[o];
  float acc0 = f, acc1 = f;
  for (int k = 0; k < 64; k++) {
    float w = ldin(aw2, k * 64 + o, f32);
    acc0 += s0[k] * w;
    acc1 += s1[k] * w;
  }
  float amv = ldin(am, o, f32);
  float p0 = tanhf(acc0) * amv;
  float p1 = tanhf(acc1) * amv;
#pragma unroll
  for (int off = 32; off > 0; off >>= 1) {
    p0 += __shfl_xor(p0, off);
    p1 += __shfl_xor(p1, off);
  }
  float mx = fmaxf(p0, p1);
  float e0 = __expf(p0 - mx), e1 = __expf(p1 - mx);
  float b0 = e0 / (e0 + e1), b1 = e1 / (e0 + e1);
  float fus = b0 * ta0 + b1 * ta1;
  float l0 = ta0 * ldin(fcw, o * 2 + 0, f32) + ta1 * ldin(fcw, (64 + o) * 2 + 0, f32) +
             fus * ldin(fcw, (128 + o) * 2 + 0, f32);
  float l1 = ta0 * ldin(fcw, o * 2 + 1, f32) + ta1 * ldin(fcw, (64 + o) * 2 + 1, f32) +
             fus * ldin(fcw, (128 + o) * 2 + 1, f32);
#pragma unroll
  for (int off = 32; off > 0; off >>= 1) {
    l0 += __shfl_xor(l0, off);
    l1 += __shfl_xor(l1, off);
  }
  if (o == 0) {
    l0 += ldin(fcb, 0, f32);
    l1 += ldin(fcb, 1, f32);
    float m2 = fmaxf(l0, l1);
    float lse = m2 + logf(__expf(l0 - m2) + __expf(l1 - m2));
    if (f32) {
      ((float*)out)[n * 2 + 0] = l0 - lse;
      ((float*)out)[n * 2 + 1] = l1 - lse;
    } else {
      ((bf16*)out)[n * 2 + 0] = __float2bfloat16(l0 - lse);
      ((bf16*)out)[n * 2 + 1] = __float2bfloat16(l1 - lse);
    }
  }
}

extern "C" void kernel_launch(void* const* d_in, const int* in_sizes, int n_in,
                              void* d_out, int out_size, void* d_ws, size_t ws_size,
                              hipStream_t stream) {
  constexpr int N = 20000, E = 320000, H = 8, F0 = 128, FU = 256, FO = 64;
  const void* hemb[2] = {d_in[0], d_in[1]};
  const void* W[2] = {d_in[2], d_in[3]};
  const void* gw[2][2] = {{d_in[4], d_in[7]}, {d_in[10], d_in[13]}};
  const void* gasrc[2][2] = {{d_in[5], d_in[8]}, {d_in[11], d_in[14]}};
  const void* gatrg[2][2] = {{d_in[6], d_in[9]}, {d_in[12], d_in[15]}};
  const void* aw1 = d_in[16];
  const void* aw2 = d_in[17];
  const void* am = d_in[18];
  const void* fcw = d_in[19];
  const void* fcb = d_in[20];
  const int* edge[2] = {(const int*)d_in[21], (const int*)d_in[22]};

  char* p = (char*)d_ws;
  auto alloc = [&](size_t bytes) -> void* {
    void* r = (void*)p;
    p += (bytes + 255) & ~(size_t)255;
    return r;
  };
  int* flag = (int*)alloc(4);
  bf16* trans = (bf16*)alloc((size_t)N * FU * 2);        // 10.24 MB
  bf16* hp = (bf16*)alloc((size_t)N * H * FO * 2);       // 20.48 MB  [N][512]
  bf16* xbuf = (bf16*)alloc((size_t)N * H * FO * 2);     // 20.48 MB  [N][512]
  float* sv = (float*)alloc((size_t)N * H * 4);          // 0.64 MB
  float* tv = (float*)alloc((size_t)N * H * 4);          // 0.64 MB
  float* ta = (float*)alloc((size_t)N * 2 * FO * 4);     // 10.24 MB
  float* favec = (float*)alloc(FO * 4);
  int* deg[2];
  int* rp[2];
  int* fil[2];
  int* col[2];
  for (int t = 0; t < 2; t++) {
    deg[t] = (int*)alloc((size_t)N * 4);
    rp[t] = (int*)alloc((size_t)(N + 1) * 4);
    fil[t] = (int*)alloc((size_t)N * 4);
    col[t] = (int*)alloc((size_t)E * 4);
  }

  detect_kernel<<<1, 64, 0, stream>>>(hemb[0], flag);

  for (int t = 0; t < 2; t++) {
    hipMemsetAsync(deg[t], 0, (size_t)N * 4, stream);
    hist_kernel<<<(E + 255) / 256, 256, 0, stream>>>(edge[t] + E, deg[t], E);
    scan_kernel<<<1, 1024, 0, stream>>>(deg[t], rp[t], fil[t], N);
    fill_kernel<<<(E + 255) / 256, 256, 0, stream>>>(edge[t], edge[t] + E, fil[t], col[t], E);
  }

  const int gmx = (N + GBM - 1) / GBM;  // 157
  const int gagg = (N + 3) / 4;         // 5000

  for (int t = 0; t < 2; t++) {
    // trans = hemb @ W  [N, FU] (bf16 ws); A dynamic input, B row-major input
    gemm_mfma<<<dim3(gmx, FU / GBN), 256, 0, stream>>>(hemb[t], 1, W[t], 0, trans,
                                                       N, F0, FU, flag);
    // hp[n][h*64+o] layer 0: single GEMM, Nc=512, B head-blocked [H][FU][64]
    gemm_mfma<<<dim3(gmx, (H * FO) / GBN), 256, 0, stream>>>(trans, 0, gw[t][0], 1, hp,
                                                             N, FU, H * FO, flag);
    st_kernel<<<(N * H + 255) / 256, 256, 0, stream>>>(hp, gasrc[t][0], gatrg[t][0], sv, tv, N, flag);
    aggregate<<<gagg, 256, 0, stream>>>(hp, sv, tv, rp[t], col[t], xbuf, N, 0);
    // hp layer 1 (input xbuf [N, 512]): Nc=512, K=512, B head-blocked [H][512][64]
    gemm_mfma<<<dim3(gmx, (H * FO) / GBN), 256, 0, stream>>>(xbuf, 0, gw[t][1], 1, hp,
                                                             N, H * FO, H * FO, flag);
    st_kernel<<<(N * H + 255) / 256, 256, 0, stream>>>(hp, gasrc[t][1], gatrg[t][1], sv, tv, N, flag);
    aggregate<<<gagg, 256, 0, stream>>>(hp, sv, tv, rp[t], col[t], ta + t * FO, N, 1);
  }

  favec_kernel<<<1, 64, 0, stream>>>(trans, aw1, favec, flag);
  final_kernel<<<N, 64, 0, stream>>>(ta, favec, aw2, am, fcw, fcb, d_out, N, flag);
}

// Round 4
// 626.489 us; speedup vs baseline: 2.1479x; 1.0548x over previous
//
#include <hip/hip_runtime.h>
#include <hip/hip_bf16.h>

// ---------------------------------------------------------------------------
// HetergatWOConcatFeat — round 6:
//  - st fused into gemm_mfma epilogue (head = blockIdx.y when bmode==1):
//    s,t computed from fp32 accumulators + 16-lane shfl reduce. st_kernel
//    deleted (-4 launches, -80MB hp re-read).
//  - aggregate: explicit double-buffered 4-edge pipeline (next loads issued
//    before current compute) -> 8 row loads in flight, continuous stream.
// ---------------------------------------------------------------------------

typedef __hip_bfloat16 bf16;
typedef __attribute__((ext_vector_type(8))) short short8;
typedef __attribute__((ext_vector_type(4))) float f32x4;

__device__ __forceinline__ float bf2f(bf16 v) { return __bfloat162float(v); }
__device__ __forceinline__ float ldin(const void* p, long i, int f32) {
  return f32 ? ((const float*)p)[i] : bf2f(((const bf16*)p)[i]);
}
__device__ __forceinline__ short f2bfbits(float f) {
  bf16 h = __float2bfloat16(f);
  return *reinterpret_cast<short*>(&h);
}
__device__ __forceinline__ float bfbits2f(short b) {
  unsigned u = ((unsigned)(unsigned short)b) << 16;
  return __uint_as_float(u);
}

// Detect input dtype: read first 2048 elements of hemb0 as bf16. If the data
// is really f32, the mantissa halves decode to huge/NaN values.
__global__ __launch_bounds__(64) void detect_kernel(const void* __restrict__ x,
                                                    int* __restrict__ flag) {
  int tid = threadIdx.x;
  float m = 0.f;
  for (int i = tid; i < 2048; i += 64) {
    float v = fabsf(bf2f(((const bf16*)x)[i]));
    if (!(v <= 1e3f)) v = 1e9f;  // NaN/Inf/big -> force detect
    m = fmaxf(m, v);
  }
#pragma unroll
  for (int off = 32; off; off >>= 1) m = fmaxf(m, __shfl_xor(m, off));
  if (tid == 0) flag[0] = (m > 1e3f) ? 1 : 0;
}

// ---------------------------------------------------------------------------
// MFMA GEMM: C[M][Nc] (bf16, row-major) = A[M][K] @ B[K][Nc], fp32 accum.
// amode: 0 = A is ws bf16 row-major; 1 = A is an input tensor (dtype by flag).
// bmode: 0 = B row-major [K][Nc] input; 1 = B head-blocked [H][K][64] input.
// Tile: BM=128, BN=64, BK=64. 256 threads = 4 waves. 16x16x32 bf16 MFMA.
// LDS: As[row][k], Bs[col][k] (B transposed), XOR swizzle -> conflict-free.
// Fused st (svp != null, requires bmode==1 so blockIdx.y == head):
//   sv[row*8+h] = sum_col acc[row][col]*asrc[h][col]  (and tv with atrg),
//   computed from fp32 acc + shfl_xor reduce over the 16 col-lanes.
// ---------------------------------------------------------------------------
#define GBM 128
#define GBN 64
#define GBK 64

__device__ __forceinline__ int swz(int row, int kbyte) {
  return row * 128 + (kbyte ^ ((row & 7) << 4));
}

__global__ __launch_bounds__(256) void gemm_mfma(const void* __restrict__ A, int amode,
                                                 const void* __restrict__ B, int bmode,
                                                 bf16* __restrict__ C,
                                                 int M, int K, int Nc,
                                                 const void* __restrict__ stasrc,
                                                 const void* __restrict__ statrg,
                                                 float* __restrict__ svp,
                                                 float* __restrict__ tvp,
                                                 const int* __restrict__ flag) {
  __shared__ bf16 As[GBM * GBK];
  __shared__ bf16 Bs[GBN * GBK];
  const int f32 = flag[0];
  const int af32 = (amode == 1) ? f32 : 0;
  const int m0 = blockIdx.x * GBM;
  const int n0 = blockIdx.y * GBN;
  const int tid = threadIdx.x;
  const int lane = tid & 63;
  const int wrow = (tid >> 6) * 32;

  f32x4 acc[2][4];
#pragma unroll
  for (int m = 0; m < 2; m++)
#pragma unroll
    for (int n = 0; n < 4; n++)
#pragma unroll
      for (int r = 0; r < 4; r++) acc[m][n][r] = 0.f;

  for (int kt = 0; kt < K; kt += GBK) {
    // ---- stage A: 128 rows x 64 k (bf16), 1024 16B slots, 4 per thread ----
#pragma unroll
    for (int j = 0; j < 4; j++) {
      int idx = tid + j * 256;       // 0..1023
      int row = idx >> 3;            // 0..127
      int ks = idx & 7;              // 16B slot within row
      int gm = m0 + row;
      short8 v;
#pragma unroll
      for (int e = 0; e < 8; e++) v[e] = 0;
      if (gm < M) {
        long base = (long)gm * K + kt + ks * 8;
        if (!af32) {
          v = *(const short8*)((const bf16*)A + base);
        } else {
          const float* Af = (const float*)A + base;
#pragma unroll
          for (int e = 0; e < 8; e++) v[e] = f2bfbits(Af[e]);
        }
      }
      *(short8*)((char*)As + swz(row, ks * 16)) = v;
    }
    // ---- stage B transposed: Bs[col][k], 64 cols x 64 k ----
    {
      int n = tid & 63;
      int ks0 = tid >> 6;  // 0..3
#pragma unroll
      for (int jj = 0; jj < 2; jj++) {
        int ks = ks0 + jj * 4;     // 0..7
        int k = kt + ks * 8;
        int col = n0 + n;
        long base;
        int cstr;
        if (bmode == 0) { base = (long)k * Nc + col; cstr = Nc; }
        else { base = ((long)(col >> 6) * K + k) * 64 + (col & 63); cstr = 64; }
        short8 v;
        if (f32) {
          const float* Bf = (const float*)B;
#pragma unroll
          for (int e = 0; e < 8; e++) v[e] = f2bfbits(Bf[base + (long)e * cstr]);
        } else {
          const bf16* Bh = (const bf16*)B;
#pragma unroll
          for (int e = 0; e < 8; e++) v[e] = *(const short*)&Bh[base + (long)e * cstr];
        }
        *(short8*)((char*)Bs + swz(n, ks * 16)) = v;
      }
    }
    __syncthreads();
    // ---- compute: 2 k-halves of 32, per wave 2x4 fragments ----
#pragma unroll
    for (int kh = 0; kh < 2; kh++) {
      int klane = kh * 64 + ((lane >> 4) << 4);  // byte offset of k within row
      short8 af[2], bfr[4];
#pragma unroll
      for (int m = 0; m < 2; m++) {
        int row = wrow + m * 16 + (lane & 15);
        af[m] = *(const short8*)((const char*)As + swz(row, klane));
      }
#pragma unroll
      for (int n = 0; n < 4; n++) {
        int col = n * 16 + (lane & 15);
        bfr[n] = *(const short8*)((const char*)Bs + swz(col, klane));
      }
#pragma unroll
      for (int m = 0; m < 2; m++)
#pragma unroll
        for (int n = 0; n < 4; n++)
          acc[m][n] = __builtin_amdgcn_mfma_f32_16x16x32_bf16(af[m], bfr[n], acc[m][n], 0, 0, 0);
    }
    __syncthreads();
  }
  // ---- fused st: s/t from fp32 acc (head h = blockIdx.y when bmode==1) ----
  if (svp) {
    const int h = blockIdx.y;
    const int cl = lane & 15;
    float av[4], bv[4];
#pragma unroll
    for (int n = 0; n < 4; n++) {
      av[n] = ldin(stasrc, h * 64 + n * 16 + cl, f32);
      bv[n] = ldin(statrg, h * 64 + n * 16 + cl, f32);
    }
#pragma unroll
    for (int m = 0; m < 2; m++) {
#pragma unroll
      for (int r = 0; r < 4; r++) {
        float s = 0.f, t = 0.f;
#pragma unroll
        for (int n = 0; n < 4; n++) {
          s += acc[m][n][r] * av[n];
          t += acc[m][n][r] * bv[n];
        }
#pragma unroll
        for (int off = 1; off <= 8; off <<= 1) {
          s += __shfl_xor(s, off);
          t += __shfl_xor(t, off);
        }
        int row = m0 + wrow + m * 16 + ((lane >> 4) << 2) + r;
        if (cl == 0 && row < M) {
          svp[(long)row * 8 + h] = s;
          tvp[(long)row * 8 + h] = t;
        }
      }
    }
  }
  // ---- C write: row = (lane>>4)*4 + reg, col = lane&15 ----
#pragma unroll
  for (int m = 0; m < 2; m++) {
#pragma unroll
    for (int r = 0; r < 4; r++) {
      int row = m0 + wrow + m * 16 + ((lane >> 4) << 2) + r;
      if (row < M) {
#pragma unroll
        for (int n = 0; n < 4; n++) {
          int col = n0 + n * 16 + (lane & 15);
          C[(long)row * Nc + col] = __float2bfloat16(acc[m][n][r]);
        }
      }
    }
  }
}

// ---- CSR build ----
__global__ void hist_kernel(const int* __restrict__ trg, int* __restrict__ deg, int E) {
  int e = blockIdx.x * 256 + threadIdx.x;
  if (e < E) atomicAdd(&deg[trg[e]], 1);
}

__global__ __launch_bounds__(1024) void scan_kernel(const int* __restrict__ deg,
                                                    int* __restrict__ row_ptr,
                                                    int* __restrict__ fil, int N) {
  __shared__ int sums[1024];
  int tid = threadIdx.x;
  int chunk = (N + 1023) >> 10;
  int start = tid * chunk;
  int end = start + chunk;
  if (start > N) start = N;
  if (end > N) end = N;
  int s = 0;
  for (int i = start; i < end; i++) s += deg[i];
  sums[tid] = s;
  __syncthreads();
  for (int off = 1; off < 1024; off <<= 1) {
    int add = (tid >= off) ? sums[tid - off] : 0;
    __syncthreads();
    sums[tid] += add;
    __syncthreads();
  }
  int run = (tid > 0) ? sums[tid - 1] : 0;
  for (int i = start; i < end; i++) {
    row_ptr[i] = run;
    fil[i] = run;
    run += deg[i];
  }
  if (tid == 0) row_ptr[N] = sums[1023];
}

__global__ void fill_kernel(const int* __restrict__ src, const int* __restrict__ trg,
                            int* __restrict__ fil, int* __restrict__ col, int E) {
  int e = blockIdx.x * 256 + threadIdx.x;
  if (e >= E) return;
  int t = trg[e];
  int pos = atomicAdd(&fil[t], 1);
  col[pos] = src[e];
}

// ---------------------------------------------------------------------------
// GAT aggregation, fused single pass: out = (Σ_e ex_e · hp[src_e]) / (Σ_e ex_e).
// One wave per node. Lane c owns bytes [c*16, c*16+16) of the 1KB row
// (head h = c>>3). Edge srcs staged one-per-lane + __shfl broadcast.
// Double-buffered 4-edge pipeline: loads for group i+1 issue before group i's
// compute -> 8 coalesced row loads in flight per wave, continuous stream.
// mode 0: bf16 out[n*512 + o] = elu(sum)
// mode 1: float out[n*128 + o] = mean_h(sum)  (caller offsets out by slot)
// ---------------------------------------------------------------------------
__device__ __forceinline__ float exleaky(float v) {
  v = v > 0.f ? v : 0.2f * v;
  return __expf(v);
}

__global__ __launch_bounds__(256) void aggregate(const bf16* __restrict__ hp,
                                                 const float* __restrict__ sv,
                                                 const float* __restrict__ tv,
                                                 const int* __restrict__ row_ptr,
                                                 const int* __restrict__ col_src,
                                                 void* __restrict__ out, int N, int mode) {
  const int wid = threadIdx.x >> 6;
  const int lane = threadIdx.x & 63;
  const int n = blockIdx.x * 4 + wid;
  if (n >= N) return;
  const int start = row_ptr[n];
  const int deg = row_ptr[n + 1] - start;
  const int h = lane >> 3;
  const float tvh = tv[(long)n * 8 + h];
  const bf16* __restrict__ hpc = hp + lane * 8;

  float acc[8] = {0.f, 0.f, 0.f, 0.f, 0.f, 0.f, 0.f, 0.f};
  float den = 1e-16f;

#define AG_LOAD(E, V0, V1, V2, V3, Q0, Q1, Q2, Q3)                  \
  {                                                                 \
    int t0 = __shfl(mysrc, (E) + 0), t1 = __shfl(mysrc, (E) + 1);   \
    int t2 = __shfl(mysrc, (E) + 2), t3 = __shfl(mysrc, (E) + 3);   \
    V0 = *(const short8*)(hpc + (long)t0 * 512);                    \
    V1 = *(const short8*)(hpc + (long)t1 * 512);                    \
    V2 = *(const short8*)(hpc + (long)t2 * 512);                    \
    V3 = *(const short8*)(hpc + (long)t3 * 512);                    \
    Q0 = sv[(long)t0 * 8 + h];                                      \
    Q1 = sv[(long)t1 * 8 + h];                                      \
    Q2 = sv[(long)t2 * 8 + h];                                      \
    Q3 = sv[(long)t3 * 8 + h];                                      \
  }
#define AG_ACC(V0, V1, V2, V3, Q0, Q1, Q2, Q3)                      \
  {                                                                 \
    float a0 = exleaky(Q0 + tvh), a1 = exleaky(Q1 + tvh);           \
    float a2 = exleaky(Q2 + tvh), a3 = exleaky(Q3 + tvh);           \
    den += a0 + a1 + a2 + a3;                                       \
    _Pragma("unroll")                                               \
    for (int j = 0; j < 8; j++)                                     \
      acc[j] += a0 * bfbits2f(V0[j]) + a1 * bfbits2f(V1[j]) +       \
                a2 * bfbits2f(V2[j]) + a3 * bfbits2f(V3[j]);        \
  }

  for (int base = 0; base < deg; base += 64) {
    int cnt = deg - base;
    if (cnt > 64) cnt = 64;
    int mysrc = (lane < cnt) ? col_src[start + base + lane] : 0;
    int nfull = cnt & ~3;
    if (nfull) {
      short8 v0, v1, v2, v3;
      float q0, q1, q2, q3;
      AG_LOAD(0, v0, v1, v2, v3, q0, q1, q2, q3);
      for (int e = 4; e < nfull; e += 4) {
        short8 w0 = v0, w1 = v1, w2 = v2, w3 = v3;
        float p0 = q0, p1 = q1, p2 = q2, p3 = q3;
        AG_LOAD(e, v0, v1, v2, v3, q0, q1, q2, q3);
        AG_ACC(w0, w1, w2, w3, p0, p1, p2, p3);
      }
      AG_ACC(v0, v1, v2, v3, q0, q1, q2, q3);
    }
    for (int e = nfull; e < cnt; e++) {
      int s0 = __shfl(mysrc, e);
      short8 v = *(const short8*)(hpc + (long)s0 * 512);
      float a = exleaky(sv[(long)s0 * 8 + h] + tvh);
      den += a;
#pragma unroll
      for (int j = 0; j < 8; j++) acc[j] += a * bfbits2f(v[j]);
    }
  }

  const float dinv = 1.f / den;
  if (mode == 0) {
    short8 o8;
#pragma unroll
    for (int j = 0; j < 8; j++) {
      float s = acc[j] * dinv;
      float ev = s > 0.f ? s : expm1f(s);
      o8[j] = f2bfbits(ev);
    }
    *(short8*)((bf16*)out + (long)n * 512 + lane * 8) = o8;
  } else {
    float r[8];
#pragma unroll
    for (int j = 0; j < 8; j++) r[j] = acc[j] * dinv;
    // sum across the 8 lanes {q, q+8, ..., q+56} (q = lane&7): heads 0..7
#pragma unroll
    for (int m = 8; m <= 32; m <<= 1)
#pragma unroll
      for (int j = 0; j < 8; j++) r[j] += __shfl_xor(r[j], m);
    if (lane < 8) {
      float* o = (float*)out + (long)n * 128 + lane * 8;
#pragma unroll
      for (int j = 0; j < 8; j++) o[j] = r[j] * 0.125f;
    }
  }
}

// favec[o] = trans1[0,:]·aw1[:,o]
__global__ __launch_bounds__(64) void favec_kernel(const bf16* __restrict__ trans1,
                                                   const void* __restrict__ aw1,
                                                   float* __restrict__ favec,
                                                   const int* __restrict__ flag) {
  const int f32 = flag[0];
  int o = threadIdx.x;
  float acc = 0.f;
  for (int k = 0; k < 256; k++) acc += bf2f(trans1[k]) * ldin(aw1, k * 64 + o, f32);
  favec[o] = acc;
}

// Semantic attention + FC + log_softmax. One wave per node.
__global__ __launch_bounds__(64) void final_kernel(const float* __restrict__ ta,
                                                   const float* __restrict__ favec,
                                                   const void* __restrict__ aw2,
                                                   const void* __restrict__ am,
                                                   const void* __restrict__ fcw,
                                                   const void* __restrict__ fcb,
                                                   void* __restrict__ out, int N,
                                                   const int* __restrict__ flag) {
  const int f32 = flag[0];
  int n = blockIdx.x;
  int o = threadIdx.x;
  __shared__ float s0[64], s1[64];
  float ta0 = ta[(long)n * 128 + o];
  float ta1 = ta[(long)n * 128 + 64 + o];
  s0[o] = ta0;
  s1[o] = ta1;
  __syncthreads();
  float f = favec[o];
  float acc0 = f, acc1 = f;
  for (int k = 0; k < 64; k++) {
    float w = ldin(aw2, k * 64 + o, f32);
    acc0 += s0[k] * w;
    acc1 += s1[k] * w;
  }
  float amv = ldin(am, o, f32);
  float p0 = tanhf(acc0) * amv;
  float p1 = tanhf(acc1) * amv;
#pragma unroll
  for (int off = 32; off > 0; off >>= 1) {
    p0 += __shfl_xor(p0, off);
    p1 += __shfl_xor(p1, off);
  }
  float mx = fmaxf(p0, p1);
  float e0 = __expf(p0 - mx), e1 = __expf(p1 - mx);
  float b0 = e0 / (e0 + e1), b1 = e1 / (e0 + e1);
  float fus = b0 * ta0 + b1 * ta1;
  float l0 = ta0 * ldin(fcw, o * 2 + 0, f32) + ta1 * ldin(fcw, (64 + o) * 2 + 0, f32) +
             fus * ldin(fcw, (128 + o) * 2 + 0, f32);
  float l1 = ta0 * ldin(fcw, o * 2 + 1, f32) + ta1 * ldin(fcw, (64 + o) * 2 + 1, f32) +
             fus * ldin(fcw, (128 + o) * 2 + 1, f32);
#pragma unroll
  for (int off = 32; off > 0; off >>= 1) {
    l0 += __shfl_xor(l0, off);
    l1 += __shfl_xor(l1, off);
  }
  if (o == 0) {
    l0 += ldin(fcb, 0, f32);
    l1 += ldin(fcb, 1, f32);
    float m2 = fmaxf(l0, l1);
    float lse = m2 + logf(__expf(l0 - m2) + __expf(l1 - m2));
    if (f32) {
      ((float*)out)[n * 2 + 0] = l0 - lse;
      ((float*)out)[n * 2 + 1] = l1 - lse;
    } else {
      ((bf16*)out)[n * 2 + 0] = __float2bfloat16(l0 - lse);
      ((bf16*)out)[n * 2 + 1] = __float2bfloat16(l1 - lse);
    }
  }
}

extern "C" void kernel_launch(void* const* d_in, const int* in_sizes, int n_in,
                              void* d_out, int out_size, void* d_ws, size_t ws_size,
                              hipStream_t stream) {
  constexpr int N = 20000, E = 320000, H = 8, F0 = 128, FU = 256, FO = 64;
  const void* hemb[2] = {d_in[0], d_in[1]};
  const void* W[2] = {d_in[2], d_in[3]};
  const void* gw[2][2] = {{d_in[4], d_in[7]}, {d_in[10], d_in[13]}};
  const void* gasrc[2][2] = {{d_in[5], d_in[8]}, {d_in[11], d_in[14]}};
  const void* gatrg[2][2] = {{d_in[6], d_in[9]}, {d_in[12], d_in[15]}};
  const void* aw1 = d_in[16];
  const void* aw2 = d_in[17];
  const void* am = d_in[18];
  const void* fcw = d_in[19];
  const void* fcb = d_in[20];
  const int* edge[2] = {(const int*)d_in[21], (const int*)d_in[22]};

  char* p = (char*)d_ws;
  auto alloc = [&](size_t bytes) -> void* {
    void* r = (void*)p;
    p += (bytes + 255) & ~(size_t)255;
    return r;
  };
  int* flag = (int*)alloc(4);
  bf16* trans = (bf16*)alloc((size_t)N * FU * 2);        // 10.24 MB
  bf16* hp = (bf16*)alloc((size_t)N * H * FO * 2);       // 20.48 MB  [N][512]
  bf16* xbuf = (bf16*)alloc((size_t)N * H * FO * 2);     // 20.48 MB  [N][512]
  float* sv = (float*)alloc((size_t)N * H * 4);          // 0.64 MB
  float* tv = (float*)alloc((size_t)N * H * 4);          // 0.64 MB
  float* ta = (float*)alloc((size_t)N * 2 * FO * 4);     // 10.24 MB
  float* favec = (float*)alloc(FO * 4);
  int* deg[2];
  int* rp[2];
  int* fil[2];
  int* col[2];
  for (int t = 0; t < 2; t++) {
    deg[t] = (int*)alloc((size_t)N * 4);
    rp[t] = (int*)alloc((size_t)(N + 1) * 4);
    fil[t] = (int*)alloc((size_t)N * 4);
    col[t] = (int*)alloc((size_t)E * 4);
  }

  detect_kernel<<<1, 64, 0, stream>>>(hemb[0], flag);

  for (int t = 0; t < 2; t++) {
    hipMemsetAsync(deg[t], 0, (size_t)N * 4, stream);
    hist_kernel<<<(E + 255) / 256, 256, 0, stream>>>(edge[t] + E, deg[t], E);
    scan_kernel<<<1, 1024, 0, stream>>>(deg[t], rp[t], fil[t], N);
    fill_kernel<<<(E + 255) / 256, 256, 0, stream>>>(edge[t], edge[t] + E, fil[t], col[t], E);
  }

  const int gmx = (N + GBM - 1) / GBM;  // 157
  const int gagg = (N + 3) / 4;         // 5000

  for (int t = 0; t < 2; t++) {
    // trans = hemb @ W  [N, FU] (bf16 ws); A dynamic input, B row-major input
    gemm_mfma<<<dim3(gmx, FU / GBN), 256, 0, stream>>>(hemb[t], 1, W[t], 0, trans,
                                                       N, F0, FU,
                                                       nullptr, nullptr, nullptr, nullptr, flag);
    // hp layer 0: Nc=512, B head-blocked [H][FU][64]; fused st
    gemm_mfma<<<dim3(gmx, (H * FO) / GBN), 256, 0, stream>>>(trans, 0, gw[t][0], 1, hp,
                                                             N, FU, H * FO,
                                                             gasrc[t][0], gatrg[t][0], sv, tv, flag);
    aggregate<<<gagg, 256, 0, stream>>>(hp, sv, tv, rp[t], col[t], xbuf, N, 0);
    // hp layer 1 (input xbuf [N, 512]): Nc=512, K=512; fused st
    gemm_mfma<<<dim3(gmx, (H * FO) / GBN), 256, 0, stream>>>(xbuf, 0, gw[t][1], 1, hp,
                                                             N, H * FO, H * FO,
                                                             gasrc[t][1], gatrg[t][1], sv, tv, flag);
    aggregate<<<gagg, 256, 0, stream>>>(hp, sv, tv, rp[t], col[t], ta + t * FO, N, 1);
  }

  favec_kernel<<<1, 64, 0, stream>>>(trans, aw1, favec, flag);
  final_kernel<<<N, 64, 0, stream>>>(ta, favec, aw2, am, fcw, fcb, d_out, N, flag);
}

// Round 5
// 609.994 us; speedup vs baseline: 2.2060x; 1.0270x over previous
//
#include <hip/hip_runtime.h>
#include <hip/hip_bf16.h>

// ---------------------------------------------------------------------------
// HetergatWOConcatFeat — round 7:
//  - aggregate: 2 waves per node (edge-group parity split) + LDS combine.
//    Per-wave serial chain halves (~2 groups of 4), wave count doubles to
//    40000 -> latency hiding via TLP instead of deeper unroll.
//  - final_kernel: 4 nodes/block, aw2/fcw/favec/am staged in LDS once per
//    block (was 16KB of aw2 re-read per node), shfl instead of LDS arrays.
//  - CSR build: both graphs in one hist/scan/fill (8 launches -> 4).
// ---------------------------------------------------------------------------

typedef __hip_bfloat16 bf16;
typedef __attribute__((ext_vector_type(8))) short short8;
typedef __attribute__((ext_vector_type(4))) float f32x4;

__device__ __forceinline__ float bf2f(bf16 v) { return __bfloat162float(v); }
__device__ __forceinline__ float ldin(const void* p, long i, int f32) {
  return f32 ? ((const float*)p)[i] : bf2f(((const bf16*)p)[i]);
}
__device__ __forceinline__ short f2bfbits(float f) {
  bf16 h = __float2bfloat16(f);
  return *reinterpret_cast<short*>(&h);
}
__device__ __forceinline__ float bfbits2f(short b) {
  unsigned u = ((unsigned)(unsigned short)b) << 16;
  return __uint_as_float(u);
}

// Detect input dtype: read first 2048 elements of hemb0 as bf16. If the data
// is really f32, the mantissa halves decode to huge/NaN values.
__global__ __launch_bounds__(64) void detect_kernel(const void* __restrict__ x,
                                                    int* __restrict__ flag) {
  int tid = threadIdx.x;
  float m = 0.f;
  for (int i = tid; i < 2048; i += 64) {
    float v = fabsf(bf2f(((const bf16*)x)[i]));
    if (!(v <= 1e3f)) v = 1e9f;  // NaN/Inf/big -> force detect
    m = fmaxf(m, v);
  }
#pragma unroll
  for (int off = 32; off; off >>= 1) m = fmaxf(m, __shfl_xor(m, off));
  if (tid == 0) flag[0] = (m > 1e3f) ? 1 : 0;
}

// ---------------------------------------------------------------------------
// MFMA GEMM: C[M][Nc] (bf16, row-major) = A[M][K] @ B[K][Nc], fp32 accum.
// amode: 0 = A is ws bf16 row-major; 1 = A is an input tensor (dtype by flag).
// bmode: 0 = B row-major [K][Nc] input; 1 = B head-blocked [H][K][64] input.
// Tile: BM=128, BN=64, BK=64. 256 threads = 4 waves. 16x16x32 bf16 MFMA.
// LDS: As[row][k], Bs[col][k] (B transposed), XOR swizzle -> conflict-free.
// Fused st (svp != null, requires bmode==1 so blockIdx.y == head):
//   sv[row*8+h] = sum_col acc[row][col]*asrc[h][col]  (and tv with atrg).
// ---------------------------------------------------------------------------
#define GBM 128
#define GBN 64
#define GBK 64

__device__ __forceinline__ int swz(int row, int kbyte) {
  return row * 128 + (kbyte ^ ((row & 7) << 4));
}

__global__ __launch_bounds__(256) void gemm_mfma(const void* __restrict__ A, int amode,
                                                 const void* __restrict__ B, int bmode,
                                                 bf16* __restrict__ C,
                                                 int M, int K, int Nc,
                                                 const void* __restrict__ stasrc,
                                                 const void* __restrict__ statrg,
                                                 float* __restrict__ svp,
                                                 float* __restrict__ tvp,
                                                 const int* __restrict__ flag) {
  __shared__ bf16 As[GBM * GBK];
  __shared__ bf16 Bs[GBN * GBK];
  const int f32 = flag[0];
  const int af32 = (amode == 1) ? f32 : 0;
  const int m0 = blockIdx.x * GBM;
  const int n0 = blockIdx.y * GBN;
  const int tid = threadIdx.x;
  const int lane = tid & 63;
  const int wrow = (tid >> 6) * 32;

  f32x4 acc[2][4];
#pragma unroll
  for (int m = 0; m < 2; m++)
#pragma unroll
    for (int n = 0; n < 4; n++)
#pragma unroll
      for (int r = 0; r < 4; r++) acc[m][n][r] = 0.f;

  for (int kt = 0; kt < K; kt += GBK) {
    // ---- stage A: 128 rows x 64 k (bf16), 1024 16B slots, 4 per thread ----
#pragma unroll
    for (int j = 0; j < 4; j++) {
      int idx = tid + j * 256;       // 0..1023
      int row = idx >> 3;            // 0..127
      int ks = idx & 7;              // 16B slot within row
      int gm = m0 + row;
      short8 v;
#pragma unroll
      for (int e = 0; e < 8; e++) v[e] = 0;
      if (gm < M) {
        long base = (long)gm * K + kt + ks * 8;
        if (!af32) {
          v = *(const short8*)((const bf16*)A + base);
        } else {
          const float* Af = (const float*)A + base;
#pragma unroll
          for (int e = 0; e < 8; e++) v[e] = f2bfbits(Af[e]);
        }
      }
      *(short8*)((char*)As + swz(row, ks * 16)) = v;
    }
    // ---- stage B transposed: Bs[col][k], 64 cols x 64 k ----
    {
      int n = tid & 63;
      int ks0 = tid >> 6;  // 0..3
#pragma unroll
      for (int jj = 0; jj < 2; jj++) {
        int ks = ks0 + jj * 4;     // 0..7
        int k = kt + ks * 8;
        int col = n0 + n;
        long base;
        int cstr;
        if (bmode == 0) { base = (long)k * Nc + col; cstr = Nc; }
        else { base = ((long)(col >> 6) * K + k) * 64 + (col & 63); cstr = 64; }
        short8 v;
        if (f32) {
          const float* Bf = (const float*)B;
#pragma unroll
          for (int e = 0; e < 8; e++) v[e] = f2bfbits(Bf[base + (long)e * cstr]);
        } else {
          const bf16* Bh = (const bf16*)B;
#pragma unroll
          for (int e = 0; e < 8; e++) v[e] = *(const short*)&Bh[base + (long)e * cstr];
        }
        *(short8*)((char*)Bs + swz(n, ks * 16)) = v;
      }
    }
    __syncthreads();
    // ---- compute: 2 k-halves of 32, per wave 2x4 fragments ----
#pragma unroll
    for (int kh = 0; kh < 2; kh++) {
      int klane = kh * 64 + ((lane >> 4) << 4);  // byte offset of k within row
      short8 af[2], bfr[4];
#pragma unroll
      for (int m = 0; m < 2; m++) {
        int row = wrow + m * 16 + (lane & 15);
        af[m] = *(const short8*)((const char*)As + swz(row, klane));
      }
#pragma unroll
      for (int n = 0; n < 4; n++) {
        int col = n * 16 + (lane & 15);
        bfr[n] = *(const short8*)((const char*)Bs + swz(col, klane));
      }
#pragma unroll
      for (int m = 0; m < 2; m++)
#pragma unroll
        for (int n = 0; n < 4; n++)
          acc[m][n] = __builtin_amdgcn_mfma_f32_16x16x32_bf16(af[m], bfr[n], acc[m][n], 0, 0, 0);
    }
    __syncthreads();
  }
  // ---- fused st: s/t from fp32 acc (head h = blockIdx.y when bmode==1) ----
  if (svp) {
    const int h = blockIdx.y;
    const int cl = lane & 15;
    float av[4], bv[4];
#pragma unroll
    for (int n = 0; n < 4; n++) {
      av[n] = ldin(stasrc, h * 64 + n * 16 + cl, f32);
      bv[n] = ldin(statrg, h * 64 + n * 16 + cl, f32);
    }
#pragma unroll
    for (int m = 0; m < 2; m++) {
#pragma unroll
      for (int r = 0; r < 4; r++) {
        float s = 0.f, t = 0.f;
#pragma unroll
        for (int n = 0; n < 4; n++) {
          s += acc[m][n][r] * av[n];
          t += acc[m][n][r] * bv[n];
        }
#pragma unroll
        for (int off = 1; off <= 8; off <<= 1) {
          s += __shfl_xor(s, off);
          t += __shfl_xor(t, off);
        }
        int row = m0 + wrow + m * 16 + ((lane >> 4) << 2) + r;
        if (cl == 0 && row < M) {
          svp[(long)row * 8 + h] = s;
          tvp[(long)row * 8 + h] = t;
        }
      }
    }
  }
  // ---- C write: row = (lane>>4)*4 + reg, col = lane&15 ----
#pragma unroll
  for (int m = 0; m < 2; m++) {
#pragma unroll
    for (int r = 0; r < 4; r++) {
      int row = m0 + wrow + m * 16 + ((lane >> 4) << 2) + r;
      if (row < M) {
#pragma unroll
        for (int n = 0; n < 4; n++) {
          int col = n0 + n * 16 + (lane & 15);
          C[(long)row * Nc + col] = __float2bfloat16(acc[m][n][r]);
        }
      }
    }
  }
}

// ---- CSR build (both graphs in one pass; deg/fil [2N], rp [2(N+1)]) ----
__global__ void hist2_kernel(const int* __restrict__ trg0, const int* __restrict__ trg1,
                             int* __restrict__ deg, int E, int N) {
  int e = blockIdx.x * 256 + threadIdx.x;
  if (e < E) atomicAdd(&deg[trg0[e]], 1);
  else if (e < 2 * E) atomicAdd(&deg[N + trg1[e - E]], 1);
}

__global__ __launch_bounds__(1024) void scan_kernel(const int* __restrict__ degb,
                                                    int* __restrict__ rpb,
                                                    int* __restrict__ filb, int N) {
  const int* deg = degb + (long)blockIdx.x * N;
  int* row_ptr = rpb + (long)blockIdx.x * (N + 1);
  int* fil = filb + (long)blockIdx.x * N;
  __shared__ int sums[1024];
  int tid = threadIdx.x;
  int chunk = (N + 1023) >> 10;
  int start = tid * chunk;
  int end = start + chunk;
  if (start > N) start = N;
  if (end > N) end = N;
  int s = 0;
  for (int i = start; i < end; i++) s += deg[i];
  sums[tid] = s;
  __syncthreads();
  for (int off = 1; off < 1024; off <<= 1) {
    int add = (tid >= off) ? sums[tid - off] : 0;
    __syncthreads();
    sums[tid] += add;
    __syncthreads();
  }
  int run = (tid > 0) ? sums[tid - 1] : 0;
  for (int i = start; i < end; i++) {
    row_ptr[i] = run;
    fil[i] = run;
    run += deg[i];
  }
  if (tid == 0) row_ptr[N] = sums[1023];
}

__global__ void fill2_kernel(const int* __restrict__ src0, const int* __restrict__ trg0,
                             const int* __restrict__ src1, const int* __restrict__ trg1,
                             int* __restrict__ filb, int* __restrict__ colb, int E, int N) {
  int e = blockIdx.x * 256 + threadIdx.x;
  if (e < E) {
    int t = trg0[e];
    int pos = atomicAdd(&filb[t], 1);
    colb[pos] = src0[e];
  } else if (e < 2 * E) {
    int ee = e - E;
    int t = trg1[ee];
    int pos = atomicAdd(&filb[N + t], 1);
    colb[E + pos] = src1[ee];
  }
}

// ---------------------------------------------------------------------------
// GAT aggregation, fused single pass: out = (Σ_e ex_e · hp[src_e]) / (Σ_e ex_e).
// TWO waves per node (edge-group parity split): 256 threads = 2 nodes x 2
// halves. Lane c owns bytes [c*16,c*16+16) of the 1KB row (head h = c>>3).
// Each wave's serial chain is ~deg/8 groups of 4 (all loads in flight);
// partial acc/den combined via small LDS buffer + one barrier.
// mode 0: bf16 out[n*512 + o] = elu(sum)
// mode 1: float out[n*128 + o] = mean_h(sum)  (caller offsets out by slot)
// ---------------------------------------------------------------------------
__device__ __forceinline__ float exleaky(float v) {
  v = v > 0.f ? v : 0.2f * v;
  return __expf(v);
}

__global__ __launch_bounds__(256) void aggregate(const bf16* __restrict__ hp,
                                                 const float* __restrict__ sv,
                                                 const float* __restrict__ tv,
                                                 const int* __restrict__ row_ptr,
                                                 const int* __restrict__ col_src,
                                                 void* __restrict__ out, int N, int mode) {
  __shared__ float s_acc[2][512];
  __shared__ float s_den[2][64];
  const int wid = threadIdx.x >> 6;
  const int lane = threadIdx.x & 63;
  const int slot = wid >> 1;   // node slot within block (0/1)
  const int half = wid & 1;    // edge-group parity handled by this wave
  const int n = blockIdx.x * 2 + slot;
  const int act = (n < N);
  int start = 0, deg = 0;
  if (act) {
    start = row_ptr[n];
    deg = row_ptr[n + 1] - start;
  }
  const int h = lane >> 3;
  const float tvh = act ? tv[(long)n * 8 + h] : 0.f;
  const bf16* __restrict__ hpc = hp + lane * 8;

  float acc[8] = {0.f, 0.f, 0.f, 0.f, 0.f, 0.f, 0.f, 0.f};
  float den = 0.f;

#define AG_LOAD(EB, V0, V1, V2, V3, Q0, Q1, Q2, Q3)                 \
  {                                                                 \
    int t0 = __shfl(mysrc, (EB) + 0), t1 = __shfl(mysrc, (EB) + 1); \
    int t2 = __shfl(mysrc, (EB) + 2), t3 = __shfl(mysrc, (EB) + 3); \
    V0 = *(const short8*)(hpc + (long)t0 * 512);                    \
    V1 = *(const short8*)(hpc + (long)t1 * 512);                    \
    V2 = *(const short8*)(hpc + (long)t2 * 512);                    \
    V3 = *(const short8*)(hpc + (long)t3 * 512);                    \
    Q0 = sv[(long)t0 * 8 + h];                                      \
    Q1 = sv[(long)t1 * 8 + h];                                      \
    Q2 = sv[(long)t2 * 8 + h];                                      \
    Q3 = sv[(long)t3 * 8 + h];                                      \
  }
#define AG_ACC(V0, V1, V2, V3, Q0, Q1, Q2, Q3)                      \
  {                                                                 \
    float a0 = exleaky(Q0 + tvh), a1 = exleaky(Q1 + tvh);           \
    float a2 = exleaky(Q2 + tvh), a3 = exleaky(Q3 + tvh);           \
    den += a0 + a1 + a2 + a3;                                       \
    _Pragma("unroll")                                               \
    for (int j = 0; j < 8; j++)                                     \
      acc[j] += a0 * bfbits2f(V0[j]) + a1 * bfbits2f(V1[j]) +       \
                a2 * bfbits2f(V2[j]) + a3 * bfbits2f(V3[j]);        \
  }

  for (int base = 0; base < deg; base += 64) {
    int cnt = deg - base;
    if (cnt > 64) cnt = 64;
    int mysrc = (lane < cnt) ? col_src[start + base + lane] : 0;
    int ngrp = cnt >> 2;
    int g = half;
    if (g < ngrp) {
      short8 v0, v1, v2, v3;
      float q0, q1, q2, q3;
      AG_LOAD(g * 4, v0, v1, v2, v3, q0, q1, q2, q3);
      for (int g2 = g + 2; g2 < ngrp; g2 += 2) {
        short8 w0 = v0, w1 = v1, w2 = v2, w3 = v3;
        float p0 = q0, p1 = q1, p2 = q2, p3 = q3;
        AG_LOAD(g2 * 4, v0, v1, v2, v3, q0, q1, q2, q3);
        AG_ACC(w0, w1, w2, w3, p0, p1, p2, p3);
      }
      AG_ACC(v0, v1, v2, v3, q0, q1, q2, q3);
    }
    if (half == 0) {
      for (int e = ngrp * 4; e < cnt; e++) {
        int s0 = __shfl(mysrc, e);
        short8 v = *(const short8*)(hpc + (long)s0 * 512);
        float a = exleaky(sv[(long)s0 * 8 + h] + tvh);
        den += a;
#pragma unroll
        for (int j = 0; j < 8; j++) acc[j] += a * bfbits2f(v[j]);
      }
    }
  }

  // combine the two halves via LDS ([j*64+lane]: conflict-free)
  if (half == 1) {
#pragma unroll
    for (int j = 0; j < 8; j++) s_acc[slot][j * 64 + lane] = acc[j];
    s_den[slot][lane] = den;
  }
  __syncthreads();
  if (half == 0 && act) {
    den += s_den[slot][lane] + 1e-16f;
#pragma unroll
    for (int j = 0; j < 8; j++) acc[j] += s_acc[slot][j * 64 + lane];
    const float dinv = 1.f / den;
    if (mode == 0) {
      short8 o8;
#pragma unroll
      for (int j = 0; j < 8; j++) {
        float s = acc[j] * dinv;
        float ev = s > 0.f ? s : expm1f(s);
        o8[j] = f2bfbits(ev);
      }
      *(short8*)((bf16*)out + (long)n * 512 + lane * 8) = o8;
    } else {
      float r[8];
#pragma unroll
      for (int j = 0; j < 8; j++) r[j] = acc[j] * dinv;
      // sum across the 8 lanes {q, q+8, ..., q+56} (q = lane&7): heads 0..7
#pragma unroll
      for (int m = 8; m <= 32; m <<= 1)
#pragma unroll
        for (int j = 0; j < 8; j++) r[j] += __shfl_xor(r[j], m);
      if (lane < 8) {
        float* o = (float*)out + (long)n * 128 + lane * 8;
#pragma unroll
        for (int j = 0; j < 8; j++) o[j] = r[j] * 0.125f;
      }
    }
  }
}

// favec[o] = trans1[0,:]·aw1[:,o]
__global__ __launch_bounds__(64) void favec_kernel(const bf16* __restrict__ trans1,
                                                   const void* __restrict__ aw1,
                                                   float* __restrict__ favec,
                                                   const int* __restrict__ flag) {
  const int f32 = flag[0];
  int o = threadIdx.x;
  float acc = 0.f;
  for (int k = 0; k < 256; k++) acc += bf2f(trans1[k]) * ldin(aw1, k * 64 + o, f32);
  favec[o] = acc;
}

// Semantic attention + FC + log_softmax. 4 nodes per 256-thread block;
// aw2 (16KB) / fcw / favec / am / fcb staged in LDS once per block.
__global__ __launch_bounds__(256) void final_kernel(const float* __restrict__ ta,
                                                    const float* __restrict__ favec,
                                                    const void* __restrict__ aw2,
                                                    const void* __restrict__ am,
                                                    const void* __restrict__ fcw,
                                                    const void* __restrict__ fcb,
                                                    void* __restrict__ out, int N,
                                                    const int* __restrict__ flag) {
  const int f32 = flag[0];
  __shared__ float s_w[64 * 64];
  __shared__ float s_fc[384];
  __shared__ float s_misc[130];  // [0:64) favec, [64:128) am, [128:130) fcb
  const int tid = threadIdx.x;
  for (int i = tid; i < 4096; i += 256) s_w[i] = ldin(aw2, i, f32);
  for (int i = tid; i < 384; i += 256) s_fc[i] = ldin(fcw, i, f32);
  if (tid < 64) s_misc[tid] = favec[tid];
  else if (tid < 128) s_misc[tid] = ldin(am, tid - 64, f32);
  else if (tid < 130) s_misc[tid] = ldin(fcb, tid - 128, f32);
  __syncthreads();
  const int o = tid & 63;
  const int n = blockIdx.x * 4 + (tid >> 6);
  if (n >= N) return;
  float ta0 = ta[(long)n * 128 + o];
  float ta1 = ta[(long)n * 128 + 64 + o];
  float acc0 = s_misc[o], acc1 = acc0;
  for (int k = 0; k < 64; k++) {
    float w = s_w[k * 64 + o];
    acc0 += __shfl(ta0, k) * w;
    acc1 += __shfl(ta1, k) * w;
  }
  float amv = s_misc[64 + o];
  float p0 = tanhf(acc0) * amv;
  float p1 = tanhf(acc1) * amv;
#pragma unroll
  for (int off = 32; off > 0; off >>= 1) {
    p0 += __shfl_xor(p0, off);
    p1 += __shfl_xor(p1, off);
  }
  float mx = fmaxf(p0, p1);
  float e0 = __expf(p0 - mx), e1 = __expf(p1 - mx);
  float b0 = e0 / (e0 + e1), b1 = e1 / (e0 + e1);
  float fus = b0 * ta0 + b1 * ta1;
  float l0 = ta0 * s_fc[o * 2 + 0] + ta1 * s_fc[(64 + o) * 2 + 0] + fus * s_fc[(128 + o) * 2 + 0];
  float l1 = ta0 * s_fc[o * 2 + 1] + ta1 * s_fc[(64 + o) * 2 + 1] + fus * s_fc[(128 + o) * 2 + 1];
#pragma unroll
  for (int off = 32; off > 0; off >>= 1) {
    l0 += __shfl_xor(l0, off);
    l1 += __shfl_xor(l1, off);
  }
  if (o == 0) {
    l0 += s_misc[128];
    l1 += s_misc[129];
    float m2 = fmaxf(l0, l1);
    float lse = m2 + logf(__expf(l0 - m2) + __expf(l1 - m2));
    if (f32) {
      ((float*)out)[n * 2 + 0] = l0 - lse;
      ((float*)out)[n * 2 + 1] = l1 - lse;
    } else {
      ((bf16*)out)[n * 2 + 0] = __float2bfloat16(l0 - lse);
      ((bf16*)out)[n * 2 + 1] = __float2bfloat16(l1 - lse);
    }
  }
}

extern "C" void kernel_launch(void* const* d_in, const int* in_sizes, int n_in,
                              void* d_out, int out_size, void* d_ws, size_t ws_size,
                              hipStream_t stream) {
  constexpr int N = 20000, E = 320000, H = 8, F0 = 128, FU = 256, FO = 64;
  const void* hemb[2] = {d_in[0], d_in[1]};
  const void* W[2] = {d_in[2], d_in[3]};
  const void* gw[2][2] = {{d_in[4], d_in[7]}, {d_in[10], d_in[13]}};
  const void* gasrc[2][2] = {{d_in[5], d_in[8]}, {d_in[11], d_in[14]}};
  const void* gatrg[2][2] = {{d_in[6], d_in[9]}, {d_in[12], d_in[15]}};
  const void* aw1 = d_in[16];
  const void* aw2 = d_in[17];
  const void* am = d_in[18];
  const void* fcw = d_in[19];
  const void* fcb = d_in[20];
  const int* edge[2] = {(const int*)d_in[21], (const int*)d_in[22]};

  char* p = (char*)d_ws;
  auto alloc = [&](size_t bytes) -> void* {
    void* r = (void*)p;
    p += (bytes + 255) & ~(size_t)255;
    return r;
  };
  int* flag = (int*)alloc(4);
  bf16* trans = (bf16*)alloc((size_t)N * FU * 2);        // 10.24 MB
  bf16* hp = (bf16*)alloc((size_t)N * H * FO * 2);       // 20.48 MB  [N][512]
  bf16* xbuf = (bf16*)alloc((size_t)N * H * FO * 2);     // 20.48 MB  [N][512]
  float* sv = (float*)alloc((size_t)N * H * 4);          // 0.64 MB
  float* tv = (float*)alloc((size_t)N * H * 4);          // 0.64 MB
  float* ta = (float*)alloc((size_t)N * 2 * FO * 4);     // 10.24 MB
  float* favec = (float*)alloc(FO * 4);
  int* degb = (int*)alloc((size_t)2 * N * 4);
  int* rpb = (int*)alloc((size_t)2 * (N + 1) * 4);
  int* filb = (int*)alloc((size_t)2 * N * 4);
  int* colb = (int*)alloc((size_t)2 * E * 4);

  detect_kernel<<<1, 64, 0, stream>>>(hemb[0], flag);

  // CSR build for both graphs in one pass
  hipMemsetAsync(degb, 0, (size_t)2 * N * 4, stream);
  hist2_kernel<<<(2 * E + 255) / 256, 256, 0, stream>>>(edge[0] + E, edge[1] + E, degb, E, N);
  scan_kernel<<<2, 1024, 0, stream>>>(degb, rpb, filb, N);
  fill2_kernel<<<(2 * E + 255) / 256, 256, 0, stream>>>(edge[0], edge[0] + E,
                                                        edge[1], edge[1] + E, filb, colb, E, N);

  const int gmx = (N + GBM - 1) / GBM;  // 157
  const int gagg = (N + 1) / 2;         // 10000

  for (int t = 0; t < 2; t++) {
    const int* rp = rpb + (size_t)t * (N + 1);
    const int* col = colb + (size_t)t * E;
    // trans = hemb @ W  [N, FU] (bf16 ws); A dynamic input, B row-major input
    gemm_mfma<<<dim3(gmx, FU / GBN), 256, 0, stream>>>(hemb[t], 1, W[t], 0, trans,
                                                       N, F0, FU,
                                                       nullptr, nullptr, nullptr, nullptr, flag);
    // hp layer 0: Nc=512, B head-blocked [H][FU][64]; fused st
    gemm_mfma<<<dim3(gmx, (H * FO) / GBN), 256, 0, stream>>>(trans, 0, gw[t][0], 1, hp,
                                                             N, FU, H * FO,
                                                             gasrc[t][0], gatrg[t][0], sv, tv, flag);
    aggregate<<<gagg, 256, 0, stream>>>(hp, sv, tv, rp, col, xbuf, N, 0);
    // hp layer 1 (input xbuf [N, 512]): Nc=512, K=512; fused st
    gemm_mfma<<<dim3(gmx, (H * FO) / GBN), 256, 0, stream>>>(xbuf, 0, gw[t][1], 1, hp,
                                                             N, H * FO, H * FO,
                                                             gasrc[t][1], gatrg[t][1], sv, tv, flag);
    aggregate<<<gagg, 256, 0, stream>>>(hp, sv, tv, rp, col, ta + t * FO, N, 1);
  }

  favec_kernel<<<1, 64, 0, stream>>>(trans, aw1, favec, flag);
  final_kernel<<<(N + 3) / 4, 256, 0, stream>>>(ta, favec, aw2, am, fcw, fcb, d_out, N, flag);
}

// Round 6
// 571.397 us; speedup vs baseline: 2.3550x; 1.0675x over previous
//
#include <hip/hip_runtime.h>
#include <hip/hip_bf16.h>

// ---------------------------------------------------------------------------
// HetergatWOConcatFeat — round 8:
//  - final_kernel rebuilt: 16 nodes/block (grid 1250). aw2/fcw/am/favec staged
//    once per block; the 16 ta rows staged in LDS interleaved [ni][k][2] so
//    the 64x64 matvec is float2-broadcast + stride-1 s_w read + 2 FMA per k.
//    No ds_bpermute on the critical path (round-7 regression: shfl broadcast
//    = 128 LDS-pipe ops/node at 28% occupancy -> 54 us).
//  - favec_kernel: 4 waves x 64-k partials + LDS combine (was one lonely
//    64-thread wave with a 256-long dependent chain).
//  - aggregate / GEMMs / CSR unchanged from round 7.
// ---------------------------------------------------------------------------

typedef __hip_bfloat16 bf16;
typedef __attribute__((ext_vector_type(8))) short short8;
typedef __attribute__((ext_vector_type(4))) float f32x4;

__device__ __forceinline__ float bf2f(bf16 v) { return __bfloat162float(v); }
__device__ __forceinline__ float ldin(const void* p, long i, int f32) {
  return f32 ? ((const float*)p)[i] : bf2f(((const bf16*)p)[i]);
}
__device__ __forceinline__ short f2bfbits(float f) {
  bf16 h = __float2bfloat16(f);
  return *reinterpret_cast<short*>(&h);
}
__device__ __forceinline__ float bfbits2f(short b) {
  unsigned u = ((unsigned)(unsigned short)b) << 16;
  return __uint_as_float(u);
}

// Detect input dtype: read first 2048 elements of hemb0 as bf16. If the data
// is really f32, the mantissa halves decode to huge/NaN values.
__global__ __launch_bounds__(64) void detect_kernel(const void* __restrict__ x,
                                                    int* __restrict__ flag) {
  int tid = threadIdx.x;
  float m = 0.f;
  for (int i = tid; i < 2048; i += 64) {
    float v = fabsf(bf2f(((const bf16*)x)[i]));
    if (!(v <= 1e3f)) v = 1e9f;  // NaN/Inf/big -> force detect
    m = fmaxf(m, v);
  }
#pragma unroll
  for (int off = 32; off; off >>= 1) m = fmaxf(m, __shfl_xor(m, off));
  if (tid == 0) flag[0] = (m > 1e3f) ? 1 : 0;
}

// ---------------------------------------------------------------------------
// MFMA GEMM: C[M][Nc] (bf16, row-major) = A[M][K] @ B[K][Nc], fp32 accum.
// amode: 0 = A is ws bf16 row-major; 1 = A is an input tensor (dtype by flag).
// bmode: 0 = B row-major [K][Nc] input; 1 = B head-blocked [H][K][64] input.
// Tile: BM=128, BN=64, BK=64. 256 threads = 4 waves. 16x16x32 bf16 MFMA.
// LDS: As[row][k], Bs[col][k] (B transposed), XOR swizzle -> conflict-free.
// Fused st (svp != null, requires bmode==1 so blockIdx.y == head):
//   sv[row*8+h] = sum_col acc[row][col]*asrc[h][col]  (and tv with atrg).
// ---------------------------------------------------------------------------
#define GBM 128
#define GBN 64
#define GBK 64

__device__ __forceinline__ int swz(int row, int kbyte) {
  return row * 128 + (kbyte ^ ((row & 7) << 4));
}

__global__ __launch_bounds__(256) void gemm_mfma(const void* __restrict__ A, int amode,
                                                 const void* __restrict__ B, int bmode,
                                                 bf16* __restrict__ C,
                                                 int M, int K, int Nc,
                                                 const void* __restrict__ stasrc,
                                                 const void* __restrict__ statrg,
                                                 float* __restrict__ svp,
                                                 float* __restrict__ tvp,
                                                 const int* __restrict__ flag) {
  __shared__ bf16 As[GBM * GBK];
  __shared__ bf16 Bs[GBN * GBK];
  const int f32 = flag[0];
  const int af32 = (amode == 1) ? f32 : 0;
  const int m0 = blockIdx.x * GBM;
  const int n0 = blockIdx.y * GBN;
  const int tid = threadIdx.x;
  const int lane = tid & 63;
  const int wrow = (tid >> 6) * 32;

  f32x4 acc[2][4];
#pragma unroll
  for (int m = 0; m < 2; m++)
#pragma unroll
    for (int n = 0; n < 4; n++)
#pragma unroll
      for (int r = 0; r < 4; r++) acc[m][n][r] = 0.f;

  for (int kt = 0; kt < K; kt += GBK) {
    // ---- stage A: 128 rows x 64 k (bf16), 1024 16B slots, 4 per thread ----
#pragma unroll
    for (int j = 0; j < 4; j++) {
      int idx = tid + j * 256;       // 0..1023
      int row = idx >> 3;            // 0..127
      int ks = idx & 7;              // 16B slot within row
      int gm = m0 + row;
      short8 v;
#pragma unroll
      for (int e = 0; e < 8; e++) v[e] = 0;
      if (gm < M) {
        long base = (long)gm * K + kt + ks * 8;
        if (!af32) {
          v = *(const short8*)((const bf16*)A + base);
        } else {
          const float* Af = (const float*)A + base;
#pragma unroll
          for (int e = 0; e < 8; e++) v[e] = f2bfbits(Af[e]);
        }
      }
      *(short8*)((char*)As + swz(row, ks * 16)) = v;
    }
    // ---- stage B transposed: Bs[col][k], 64 cols x 64 k ----
    {
      int n = tid & 63;
      int ks0 = tid >> 6;  // 0..3
#pragma unroll
      for (int jj = 0; jj < 2; jj++) {
        int ks = ks0 + jj * 4;     // 0..7
        int k = kt + ks * 8;
        int col = n0 + n;
        long base;
        int cstr;
        if (bmode == 0) { base = (long)k * Nc + col; cstr = Nc; }
        else { base = ((long)(col >> 6) * K + k) * 64 + (col & 63); cstr = 64; }
        short8 v;
        if (f32) {
          const float* Bf = (const float*)B;
#pragma unroll
          for (int e = 0; e < 8; e++) v[e] = f2bfbits(Bf[base + (long)e * cstr]);
        } else {
          const bf16* Bh = (const bf16*)B;
#pragma unroll
          for (int e = 0; e < 8; e++) v[e] = *(const short*)&Bh[base + (long)e * cstr];
        }
        *(short8*)((char*)Bs + swz(n, ks * 16)) = v;
      }
    }
    __syncthreads();
    // ---- compute: 2 k-halves of 32, per wave 2x4 fragments ----
#pragma unroll
    for (int kh = 0; kh < 2; kh++) {
      int klane = kh * 64 + ((lane >> 4) << 4);  // byte offset of k within row
      short8 af[2], bfr[4];
#pragma unroll
      for (int m = 0; m < 2; m++) {
        int row = wrow + m * 16 + (lane & 15);
        af[m] = *(const short8*)((const char*)As + swz(row, klane));
      }
#pragma unroll
      for (int n = 0; n < 4; n++) {
        int col = n * 16 + (lane & 15);
        bfr[n] = *(const short8*)((const char*)Bs + swz(col, klane));
      }
#pragma unroll
      for (int m = 0; m < 2; m++)
#pragma unroll
        for (int n = 0; n < 4; n++)
          acc[m][n] = __builtin_amdgcn_mfma_f32_16x16x32_bf16(af[m], bfr[n], acc[m][n], 0, 0, 0);
    }
    __syncthreads();
  }
  // ---- fused st: s/t from fp32 acc (head h = blockIdx.y when bmode==1) ----
  if (svp) {
    const int h = blockIdx.y;
    const int cl = lane & 15;
    float av[4], bv[4];
#pragma unroll
    for (int n = 0; n < 4; n++) {
      av[n] = ldin(stasrc, h * 64 + n * 16 + cl, f32);
      bv[n] = ldin(statrg, h * 64 + n * 16 + cl, f32);
    }
#pragma unroll
    for (int m = 0; m < 2; m++) {
#pragma unroll
      for (int r = 0; r < 4; r++) {
        float s = 0.f, t = 0.f;
#pragma unroll
        for (int n = 0; n < 4; n++) {
          s += acc[m][n][r] * av[n];
          t += acc[m][n][r] * bv[n];
        }
#pragma unroll
        for (int off = 1; off <= 8; off <<= 1) {
          s += __shfl_xor(s, off);
          t += __shfl_xor(t, off);
        }
        int row = m0 + wrow + m * 16 + ((lane >> 4) << 2) + r;
        if (cl == 0 && row < M) {
          svp[(long)row * 8 + h] = s;
          tvp[(long)row * 8 + h] = t;
        }
      }
    }
  }
  // ---- C write: row = (lane>>4)*4 + reg, col = lane&15 ----
#pragma unroll
  for (int m = 0; m < 2; m++) {
#pragma unroll
    for (int r = 0; r < 4; r++) {
      int row = m0 + wrow + m * 16 + ((lane >> 4) << 2) + r;
      if (row < M) {
#pragma unroll
        for (int n = 0; n < 4; n++) {
          int col = n0 + n * 16 + (lane & 15);
          C[(long)row * Nc + col] = __float2bfloat16(acc[m][n][r]);
        }
      }
    }
  }
}

// ---- CSR build (both graphs in one pass; deg/fil [2N], rp [2(N+1)]) ----
__global__ void hist2_kernel(const int* __restrict__ trg0, const int* __restrict__ trg1,
                             int* __restrict__ deg, int E, int N) {
  int e = blockIdx.x * 256 + threadIdx.x;
  if (e < E) atomicAdd(&deg[trg0[e]], 1);
  else if (e < 2 * E) atomicAdd(&deg[N + trg1[e - E]], 1);
}

__global__ __launch_bounds__(1024) void scan_kernel(const int* __restrict__ degb,
                                                    int* __restrict__ rpb,
                                                    int* __restrict__ filb, int N) {
  const int* deg = degb + (long)blockIdx.x * N;
  int* row_ptr = rpb + (long)blockIdx.x * (N + 1);
  int* fil = filb + (long)blockIdx.x * N;
  __shared__ int sums[1024];
  int tid = threadIdx.x;
  int chunk = (N + 1023) >> 10;
  int start = tid * chunk;
  int end = start + chunk;
  if (start > N) start = N;
  if (end > N) end = N;
  int s = 0;
  for (int i = start; i < end; i++) s += deg[i];
  sums[tid] = s;
  __syncthreads();
  for (int off = 1; off < 1024; off <<= 1) {
    int add = (tid >= off) ? sums[tid - off] : 0;
    __syncthreads();
    sums[tid] += add;
    __syncthreads();
  }
  int run = (tid > 0) ? sums[tid - 1] : 0;
  for (int i = start; i < end; i++) {
    row_ptr[i] = run;
    fil[i] = run;
    run += deg[i];
  }
  if (tid == 0) row_ptr[N] = sums[1023];
}

__global__ void fill2_kernel(const int* __restrict__ src0, const int* __restrict__ trg0,
                             const int* __restrict__ src1, const int* __restrict__ trg1,
                             int* __restrict__ filb, int* __restrict__ colb, int E, int N) {
  int e = blockIdx.x * 256 + threadIdx.x;
  if (e < E) {
    int t = trg0[e];
    int pos = atomicAdd(&filb[t], 1);
    colb[pos] = src0[e];
  } else if (e < 2 * E) {
    int ee = e - E;
    int t = trg1[ee];
    int pos = atomicAdd(&filb[N + t], 1);
    colb[E + pos] = src1[ee];
  }
}

// ---------------------------------------------------------------------------
// GAT aggregation, fused single pass: out = (Σ_e ex_e · hp[src_e]) / (Σ_e ex_e).
// TWO waves per node (edge-group parity split): 256 threads = 2 nodes x 2
// halves. Lane c owns bytes [c*16,c*16+16) of the 1KB row (head h = c>>3).
// Each wave's serial chain is ~deg/8 groups of 4 (all loads in flight);
// partial acc/den combined via small LDS buffer + one barrier.
// mode 0: bf16 out[n*512 + o] = elu(sum)
// mode 1: float out[n*128 + o] = mean_h(sum)  (caller offsets out by slot)
// ---------------------------------------------------------------------------
__device__ __forceinline__ float exleaky(float v) {
  v = v > 0.f ? v : 0.2f * v;
  return __expf(v);
}

__global__ __launch_bounds__(256) void aggregate(const bf16* __restrict__ hp,
                                                 const float* __restrict__ sv,
                                                 const float* __restrict__ tv,
                                                 const int* __restrict__ row_ptr,
                                                 const int* __restrict__ col_src,
                                                 void* __restrict__ out, int N, int mode) {
  __shared__ float s_acc[2][512];
  __shared__ float s_den[2][64];
  const int wid = threadIdx.x >> 6;
  const int lane = threadIdx.x & 63;
  const int slot = wid >> 1;   // node slot within block (0/1)
  const int half = wid & 1;    // edge-group parity handled by this wave
  const int n = blockIdx.x * 2 + slot;
  const int act = (n < N);
  int start = 0, deg = 0;
  if (act) {
    start = row_ptr[n];
    deg = row_ptr[n + 1] - start;
  }
  const int h = lane >> 3;
  const float tvh = act ? tv[(long)n * 8 + h] : 0.f;
  const bf16* __restrict__ hpc = hp + lane * 8;

  float acc[8] = {0.f, 0.f, 0.f, 0.f, 0.f, 0.f, 0.f, 0.f};
  float den = 0.f;

#define AG_LOAD(EB, V0, V1, V2, V3, Q0, Q1, Q2, Q3)                 \
  {                                                                 \
    int t0 = __shfl(mysrc, (EB) + 0), t1 = __shfl(mysrc, (EB) + 1); \
    int t2 = __shfl(mysrc, (EB) + 2), t3 = __shfl(mysrc, (EB) + 3); \
    V0 = *(const short8*)(hpc + (long)t0 * 512);                    \
    V1 = *(const short8*)(hpc + (long)t1 * 512);                    \
    V2 = *(const short8*)(hpc + (long)t2 * 512);                    \
    V3 = *(const short8*)(hpc + (long)t3 * 512);                    \
    Q0 = sv[(long)t0 * 8 + h];                                      \
    Q1 = sv[(long)t1 * 8 + h];                                      \
    Q2 = sv[(long)t2 * 8 + h];                                      \
    Q3 = sv[(long)t3 * 8 + h];                                      \
  }
#define AG_ACC(V0, V1, V2, V3, Q0, Q1, Q2, Q3)                      \
  {                                                                 \
    float a0 = exleaky(Q0 + tvh), a1 = exleaky(Q1 + tvh);           \
    float a2 = exleaky(Q2 + tvh), a3 = exleaky(Q3 + tvh);           \
    den += a0 + a1 + a2 + a3;                                       \
    _Pragma("unroll")                                               \
    for (int j = 0; j < 8; j++)                                     \
      acc[j] += a0 * bfbits2f(V0[j]) + a1 * bfbits2f(V1[j]) +       \
                a2 * bfbits2f(V2[j]) + a3 * bfbits2f(V3[j]);        \
  }

  for (int base = 0; base < deg; base += 64) {
    int cnt = deg - base;
    if (cnt > 64) cnt = 64;
    int mysrc = (lane < cnt) ? col_src[start + base + lane] : 0;
    int ngrp = cnt >> 2;
    int g = half;
    if (g < ngrp) {
      short8 v0, v1, v2, v3;
      float q0, q1, q2, q3;
      AG_LOAD(g * 4, v0, v1, v2, v3, q0, q1, q2, q3);
      for (int g2 = g + 2; g2 < ngrp; g2 += 2) {
        short8 w0 = v0, w1 = v1, w2 = v2, w3 = v3;
        float p0 = q0, p1 = q1, p2 = q2, p3 = q3;
        AG_LOAD(g2 * 4, v0, v1, v2, v3, q0, q1, q2, q3);
        AG_ACC(w0, w1, w2, w3, p0, p1, p2, p3);
      }
      AG_ACC(v0, v1, v2, v3, q0, q1, q2, q3);
    }
    if (half == 0) {
      for (int e = ngrp * 4; e < cnt; e++) {
        int s0 = __shfl(mysrc, e);
        short8 v = *(const short8*)(hpc + (long)s0 * 512);
        float a = exleaky(sv[(long)s0 * 8 + h] + tvh);
        den += a;
#pragma unroll
        for (int j = 0; j < 8; j++) acc[j] += a * bfbits2f(v[j]);
      }
    }
  }

  // combine the two halves via LDS ([j*64+lane]: conflict-free)
  if (half == 1) {
#pragma unroll
    for (int j = 0; j < 8; j++) s_acc[slot][j * 64 + lane] = acc[j];
    s_den[slot][lane] = den;
  }
  __syncthreads();
  if (half == 0 && act) {
    den += s_den[slot][lane] + 1e-16f;
#pragma unroll
    for (int j = 0; j < 8; j++) acc[j] += s_acc[slot][j * 64 + lane];
    const float dinv = 1.f / den;
    if (mode == 0) {
      short8 o8;
#pragma unroll
      for (int j = 0; j < 8; j++) {
        float s = acc[j] * dinv;
        float ev = s > 0.f ? s : expm1f(s);
        o8[j] = f2bfbits(ev);
      }
      *(short8*)((bf16*)out + (long)n * 512 + lane * 8) = o8;
    } else {
      float r[8];
#pragma unroll
      for (int j = 0; j < 8; j++) r[j] = acc[j] * dinv;
      // sum across the 8 lanes {q, q+8, ..., q+56} (q = lane&7): heads 0..7
#pragma unroll
      for (int m = 8; m <= 32; m <<= 1)
#pragma unroll
        for (int j = 0; j < 8; j++) r[j] += __shfl_xor(r[j], m);
      if (lane < 8) {
        float* o = (float*)out + (long)n * 128 + lane * 8;
#pragma unroll
        for (int j = 0; j < 8; j++) o[j] = r[j] * 0.125f;
      }
    }
  }
}

// favec[o] = trans1[0,:]·aw1[:,o] — 4 waves, each a 64-k partial, LDS combine.
__global__ __launch_bounds__(256) void favec_kernel(const bf16* __restrict__ trans1,
                                                    const void* __restrict__ aw1,
                                                    float* __restrict__ favec,
                                                    const int* __restrict__ flag) {
  const int f32 = flag[0];
  __shared__ float part[4][64];
  const int o = threadIdx.x & 63;
  const int wv = threadIdx.x >> 6;
  float acc = 0.f;
#pragma unroll
  for (int kk = 0; kk < 64; kk++) {
    int k = wv * 64 + kk;
    acc += bf2f(trans1[k]) * ldin(aw1, (long)k * 64 + o, f32);
  }
  part[wv][o] = acc;
  __syncthreads();
  if (threadIdx.x < 64) favec[o] = part[0][o] + part[1][o] + part[2][o] + part[3][o];
}

// ---------------------------------------------------------------------------
// Semantic attention + FC + log_softmax. 16 nodes per 256-thread block
// (4 waves x 4 nodes serial). Staged once per block: aw2 (16KB, [k][o]),
// fcw, favec/am/fcb, plus the 16 ta rows interleaved s_ta[ni][k][{ta0,ta1}]
// so the matvec inner loop = float2 same-address broadcast + stride-1 s_w
// read + 2 FMA. No ds_bpermute anywhere on the critical path.
// ---------------------------------------------------------------------------
#define FN 16
__global__ __launch_bounds__(256) void final_kernel(const float* __restrict__ ta,
                                                    const float* __restrict__ favec,
                                                    const void* __restrict__ aw2,
                                                    const void* __restrict__ am,
                                                    const void* __restrict__ fcw,
                                                    const void* __restrict__ fcb,
                                                    void* __restrict__ out, int N,
                                                    const int* __restrict__ flag) {
  const int f32 = flag[0];
  __shared__ float s_w[64 * 64];
  __shared__ float s_fc[384];
  __shared__ float s_misc[130];     // [0:64) favec, [64:128) am, [128:130) fcb
  __shared__ float s_ta[FN * 128];  // [ni][k][r] : ta0/ta1 interleaved
  const int tid = threadIdx.x;
  const int n0 = blockIdx.x * FN;
  for (int i = tid; i < 4096; i += 256) s_w[i] = ldin(aw2, i, f32);
  for (int i = tid; i < 384; i += 256) s_fc[i] = ldin(fcw, i, f32);
  if (tid < 64) s_misc[tid] = favec[tid];
  else if (tid < 128) s_misc[tid] = ldin(am, tid - 64, f32);
  else if (tid < 130) s_misc[tid] = ldin(fcb, tid - 128, f32);
  for (int idx = tid; idx < FN * 128; idx += 256) {
    int ni = idx >> 7;
    int j = idx & 127;
    int k = j >> 1, r = j & 1;
    int n = n0 + ni;
    s_ta[idx] = (n < N) ? ta[(long)n * 128 + r * 64 + k] : 0.f;
  }
  __syncthreads();
  const int o = tid & 63;
  const int wv = tid >> 6;
#pragma unroll
  for (int ni4 = 0; ni4 < 4; ni4++) {
    const int ni = wv * 4 + ni4;
    const int n = n0 + ni;
    if (n >= N) continue;
    const float* tb = &s_ta[ni * 128];
    float acc0 = s_misc[o], acc1 = acc0;
#pragma unroll 8
    for (int k = 0; k < 64; k++) {
      float2 t2 = *(const float2*)(tb + k * 2);  // broadcast (same addr)
      float w = s_w[k * 64 + o];
      acc0 += t2.x * w;
      acc1 += t2.y * w;
    }
    float ta0 = tb[o * 2];
    float ta1 = tb[o * 2 + 1];
    float amv = s_misc[64 + o];
    float p0 = tanhf(acc0) * amv;
    float p1 = tanhf(acc1) * amv;
#pragma unroll
    for (int off = 32; off > 0; off >>= 1) {
      p0 += __shfl_xor(p0, off);
      p1 += __shfl_xor(p1, off);
    }
    float mx = fmaxf(p0, p1);
    float e0 = __expf(p0 - mx), e1 = __expf(p1 - mx);
    float b0 = e0 / (e0 + e1), b1 = e1 / (e0 + e1);
    float fus = b0 * ta0 + b1 * ta1;
    float l0 = ta0 * s_fc[o * 2 + 0] + ta1 * s_fc[(64 + o) * 2 + 0] + fus * s_fc[(128 + o) * 2 + 0];
    float l1 = ta0 * s_fc[o * 2 + 1] + ta1 * s_fc[(64 + o) * 2 + 1] + fus * s_fc[(128 + o) * 2 + 1];
#pragma unroll
    for (int off = 32; off > 0; off >>= 1) {
      l0 += __shfl_xor(l0, off);
      l1 += __shfl_xor(l1, off);
    }
    if (o == 0) {
      l0 += s_misc[128];
      l1 += s_misc[129];
      float m2 = fmaxf(l0, l1);
      float lse = m2 + logf(__expf(l0 - m2) + __expf(l1 - m2));
      if (f32) {
        ((float*)out)[n * 2 + 0] = l0 - lse;
        ((float*)out)[n * 2 + 1] = l1 - lse;
      } else {
        ((bf16*)out)[n * 2 + 0] = __float2bfloat16(l0 - lse);
        ((bf16*)out)[n * 2 + 1] = __float2bfloat16(l1 - lse);
      }
    }
  }
}

extern "C" void kernel_launch(void* const* d_in, const int* in_sizes, int n_in,
                              void* d_out, int out_size, void* d_ws, size_t ws_size,
                              hipStream_t stream) {
  constexpr int N = 20000, E = 320000, H = 8, F0 = 128, FU = 256, FO = 64;
  const void* hemb[2] = {d_in[0], d_in[1]};
  const void* W[2] = {d_in[2], d_in[3]};
  const void* gw[2][2] = {{d_in[4], d_in[7]}, {d_in[10], d_in[13]}};
  const void* gasrc[2][2] = {{d_in[5], d_in[8]}, {d_in[11], d_in[14]}};
  const void* gatrg[2][2] = {{d_in[6], d_in[9]}, {d_in[12], d_in[15]}};
  const void* aw1 = d_in[16];
  const void* aw2 = d_in[17];
  const void* am = d_in[18];
  const void* fcw = d_in[19];
  const void* fcb = d_in[20];
  const int* edge[2] = {(const int*)d_in[21], (const int*)d_in[22]};

  char* p = (char*)d_ws;
  auto alloc = [&](size_t bytes) -> void* {
    void* r = (void*)p;
    p += (bytes + 255) & ~(size_t)255;
    return r;
  };
  int* flag = (int*)alloc(4);
  bf16* trans = (bf16*)alloc((size_t)N * FU * 2);        // 10.24 MB
  bf16* hp = (bf16*)alloc((size_t)N * H * FO * 2);       // 20.48 MB  [N][512]
  bf16* xbuf = (bf16*)alloc((size_t)N * H * FO * 2);     // 20.48 MB  [N][512]
  float* sv = (float*)alloc((size_t)N * H * 4);          // 0.64 MB
  float* tv = (float*)alloc((size_t)N * H * 4);          // 0.64 MB
  float* ta = (float*)alloc((size_t)N * 2 * FO * 4);     // 10.24 MB
  float* favec = (float*)alloc(FO * 4);
  int* degb = (int*)alloc((size_t)2 * N * 4);
  int* rpb = (int*)alloc((size_t)2 * (N + 1) * 4);
  int* filb = (int*)alloc((size_t)2 * N * 4);
  int* colb = (int*)alloc((size_t)2 * E * 4);

  detect_kernel<<<1, 64, 0, stream>>>(hemb[0], flag);

  // CSR build for both graphs in one pass
  hipMemsetAsync(degb, 0, (size_t)2 * N * 4, stream);
  hist2_kernel<<<(2 * E + 255) / 256, 256, 0, stream>>>(edge[0] + E, edge[1] + E, degb, E, N);
  scan_kernel<<<2, 1024, 0, stream>>>(degb, rpb, filb, N);
  fill2_kernel<<<(2 * E + 255) / 256, 256, 0, stream>>>(edge[0], edge[0] + E,
                                                        edge[1], edge[1] + E, filb, colb, E, N);

  const int gmx = (N + GBM - 1) / GBM;  // 157
  const int gagg = (N + 1) / 2;         // 10000

  for (int t = 0; t < 2; t++) {
    const int* rp = rpb + (size_t)t * (N + 1);
    const int* col = colb + (size_t)t * E;
    // trans = hemb @ W  [N, FU] (bf16 ws); A dynamic input, B row-major input
    gemm_mfma<<<dim3(gmx, FU / GBN), 256, 0, stream>>>(hemb[t], 1, W[t], 0, trans,
                                                       N, F0, FU,
                                                       nullptr, nullptr, nullptr, nullptr, flag);
    // hp layer 0: Nc=512, B head-blocked [H][FU][64]; fused st
    gemm_mfma<<<dim3(gmx, (H * FO) / GBN), 256, 0, stream>>>(trans, 0, gw[t][0], 1, hp,
                                                             N, FU, H * FO,
                                                             gasrc[t][0], gatrg[t][0], sv, tv, flag);
    aggregate<<<gagg, 256, 0, stream>>>(hp, sv, tv, rp, col, xbuf, N, 0);
    // hp layer 1 (input xbuf [N, 512]): Nc=512, K=512; fused st
    gemm_mfma<<<dim3(gmx, (H * FO) / GBN), 256, 0, stream>>>(xbuf, 0, gw[t][1], 1, hp,
                                                             N, H * FO, H * FO,
                                                             gasrc[t][1], gatrg[t][1], sv, tv, flag);
    aggregate<<<gagg, 256, 0, stream>>>(hp, sv, tv, rp, col, ta + t * FO, N, 1);
  }

  favec_kernel<<<1, 256, 0, stream>>>(trans, aw1, favec, flag);
  final_kernel<<<(N + FN - 1) / FN, 256, 0, stream>>>(ta, favec, aw2, am, fcw, fcb, d_out, N, flag);
}

// Round 7
// 542.602 us; speedup vs baseline: 2.4800x; 1.0531x over previous
//
#include <hip/hip_runtime.h>
#include <hip/hip_bf16.h>

// ---------------------------------------------------------------------------
// HetergatWOConcatFeat — round 9:
//  - grid.z type-batching: both independent type-chains (t=0,1) run in the
//    SAME launches (trans, l0, agg0, l1, agg1) via pointer-pair structs
//    indexed by blockIdx.z/y. 10 mid-pipeline launches -> 5; type-1 blocks
//    fill type-0 tails. Buffers doubled (~118 MB) behind a ws_size check
//    (fallback = round-8 sequential path, same kernels).
//  - aggregate reverted to round-6 wave-per-node (47.8us vs 50us for the
//    2-wave split: TLP split confirmed not helpful -> memory floor).
//  - final/favec/CSR/GEMM inner loops unchanged from round 8.
// ---------------------------------------------------------------------------

typedef __hip_bfloat16 bf16;
typedef __attribute__((ext_vector_type(8))) short short8;
typedef __attribute__((ext_vector_type(4))) float f32x4;

__device__ __forceinline__ float bf2f(bf16 v) { return __bfloat162float(v); }
__device__ __forceinline__ float ldin(const void* p, long i, int f32) {
  return f32 ? ((const float*)p)[i] : bf2f(((const bf16*)p)[i]);
}
__device__ __forceinline__ short f2bfbits(float f) {
  bf16 h = __float2bfloat16(f);
  return *reinterpret_cast<short*>(&h);
}
__device__ __forceinline__ float bfbits2f(short b) {
  unsigned u = ((unsigned)(unsigned short)b) << 16;
  return __uint_as_float(u);
}

struct GArg {
  const void* A[2];
  const void* B[2];
  bf16* C[2];
  const void* sa[2];
  const void* sb[2];
  float* sv[2];
  float* tv[2];
};

struct AArg {
  const bf16* hp[2];
  const float* sv[2];
  const float* tv[2];
  const int* rp[2];
  const int* col[2];
  void* out[2];
};

// Detect input dtype: read first 2048 elements of hemb0 as bf16. If the data
// is really f32, the mantissa halves decode to huge/NaN values.
__global__ __launch_bounds__(64) void detect_kernel(const void* __restrict__ x,
                                                    int* __restrict__ flag) {
  int tid = threadIdx.x;
  float m = 0.f;
  for (int i = tid; i < 2048; i += 64) {
    float v = fabsf(bf2f(((const bf16*)x)[i]));
    if (!(v <= 1e3f)) v = 1e9f;  // NaN/Inf/big -> force detect
    m = fmaxf(m, v);
  }
#pragma unroll
  for (int off = 32; off; off >>= 1) m = fmaxf(m, __shfl_xor(m, off));
  if (tid == 0) flag[0] = (m > 1e3f) ? 1 : 0;
}

// ---------------------------------------------------------------------------
// MFMA GEMM: C[M][Nc] (bf16, row-major) = A[M][K] @ B[K][Nc], fp32 accum.
// amode: 0 = A ws bf16 row-major; 1 = A input tensor (dtype by flag).
// bmode: 0 = B row-major [K][Nc] input; 1 = B head-blocked [H][K][64] input.
// blockIdx.z selects the type-slot in GArg. Fused st when sv[z] != null.
// ---------------------------------------------------------------------------
#define GBM 128
#define GBN 64
#define GBK 64

__device__ __forceinline__ int swz(int row, int kbyte) {
  return row * 128 + (kbyte ^ ((row & 7) << 4));
}

__global__ __launch_bounds__(256) void gemm_mfma(GArg g, int amode, int bmode,
                                                 int M, int K, int Nc,
                                                 const int* __restrict__ flag) {
  __shared__ bf16 As[GBM * GBK];
  __shared__ bf16 Bs[GBN * GBK];
  const int z = blockIdx.z;
  const void* __restrict__ A = g.A[z];
  const void* __restrict__ B = g.B[z];
  bf16* __restrict__ C = g.C[z];
  const void* stasrc = g.sa[z];
  const void* statrg = g.sb[z];
  float* svp = g.sv[z];
  float* tvp = g.tv[z];
  const int f32 = flag[0];
  const int af32 = (amode == 1) ? f32 : 0;
  const int m0 = blockIdx.x * GBM;
  const int n0 = blockIdx.y * GBN;
  const int tid = threadIdx.x;
  const int lane = tid & 63;
  const int wrow = (tid >> 6) * 32;

  f32x4 acc[2][4];
#pragma unroll
  for (int m = 0; m < 2; m++)
#pragma unroll
    for (int n = 0; n < 4; n++)
#pragma unroll
      for (int r = 0; r < 4; r++) acc[m][n][r] = 0.f;

  for (int kt = 0; kt < K; kt += GBK) {
    // ---- stage A: 128 rows x 64 k (bf16), 1024 16B slots, 4 per thread ----
#pragma unroll
    for (int j = 0; j < 4; j++) {
      int idx = tid + j * 256;       // 0..1023
      int row = idx >> 3;            // 0..127
      int ks = idx & 7;              // 16B slot within row
      int gm = m0 + row;
      short8 v;
#pragma unroll
      for (int e = 0; e < 8; e++) v[e] = 0;
      if (gm < M) {
        long base = (long)gm * K + kt + ks * 8;
        if (!af32) {
          v = *(const short8*)((const bf16*)A + base);
        } else {
          const float* Af = (const float*)A + base;
#pragma unroll
          for (int e = 0; e < 8; e++) v[e] = f2bfbits(Af[e]);
        }
      }
      *(short8*)((char*)As + swz(row, ks * 16)) = v;
    }
    // ---- stage B transposed: Bs[col][k], 64 cols x 64 k ----
    {
      int n = tid & 63;
      int ks0 = tid >> 6;  // 0..3
#pragma unroll
      for (int jj = 0; jj < 2; jj++) {
        int ks = ks0 + jj * 4;     // 0..7
        int k = kt + ks * 8;
        int col = n0 + n;
        long base;
        int cstr;
        if (bmode == 0) { base = (long)k * Nc + col; cstr = Nc; }
        else { base = ((long)(col >> 6) * K + k) * 64 + (col & 63); cstr = 64; }
        short8 v;
        if (f32) {
          const float* Bf = (const float*)B;
#pragma unroll
          for (int e = 0; e < 8; e++) v[e] = f2bfbits(Bf[base + (long)e * cstr]);
        } else {
          const bf16* Bh = (const bf16*)B;
#pragma unroll
          for (int e = 0; e < 8; e++) v[e] = *(const short*)&Bh[base + (long)e * cstr];
        }
        *(short8*)((char*)Bs + swz(n, ks * 16)) = v;
      }
    }
    __syncthreads();
    // ---- compute: 2 k-halves of 32, per wave 2x4 fragments ----
#pragma unroll
    for (int kh = 0; kh < 2; kh++) {
      int klane = kh * 64 + ((lane >> 4) << 4);  // byte offset of k within row
      short8 af[2], bfr[4];
#pragma unroll
      for (int m = 0; m < 2; m++) {
        int row = wrow + m * 16 + (lane & 15);
        af[m] = *(const short8*)((const char*)As + swz(row, klane));
      }
#pragma unroll
      for (int n = 0; n < 4; n++) {
        int col = n * 16 + (lane & 15);
        bfr[n] = *(const short8*)((const char*)Bs + swz(col, klane));
      }
#pragma unroll
      for (int m = 0; m < 2; m++)
#pragma unroll
        for (int n = 0; n < 4; n++)
          acc[m][n] = __builtin_amdgcn_mfma_f32_16x16x32_bf16(af[m], bfr[n], acc[m][n], 0, 0, 0);
    }
    __syncthreads();
  }
  // ---- fused st: s/t from fp32 acc (head h = blockIdx.y when bmode==1) ----
  if (svp) {
    const int h = blockIdx.y;
    const int cl = lane & 15;
    float av[4], bv[4];
#pragma unroll
    for (int n = 0; n < 4; n++) {
      av[n] = ldin(stasrc, h * 64 + n * 16 + cl, f32);
      bv[n] = ldin(statrg, h * 64 + n * 16 + cl, f32);
    }
#pragma unroll
    for (int m = 0; m < 2; m++) {
#pragma unroll
      for (int r = 0; r < 4; r++) {
        float s = 0.f, t = 0.f;
#pragma unroll
        for (int n = 0; n < 4; n++) {
          s += acc[m][n][r] * av[n];
          t += acc[m][n][r] * bv[n];
        }
#pragma unroll
        for (int off = 1; off <= 8; off <<= 1) {
          s += __shfl_xor(s, off);
          t += __shfl_xor(t, off);
        }
        int row = m0 + wrow + m * 16 + ((lane >> 4) << 2) + r;
        if (cl == 0 && row < M) {
          svp[(long)row * 8 + h] = s;
          tvp[(long)row * 8 + h] = t;
        }
      }
    }
  }
  // ---- C write: row = (lane>>4)*4 + reg, col = lane&15 ----
#pragma unroll
  for (int m = 0; m < 2; m++) {
#pragma unroll
    for (int r = 0; r < 4; r++) {
      int row = m0 + wrow + m * 16 + ((lane >> 4) << 2) + r;
      if (row < M) {
#pragma unroll
        for (int n = 0; n < 4; n++) {
          int col = n0 + n * 16 + (lane & 15);
          C[(long)row * Nc + col] = __float2bfloat16(acc[m][n][r]);
        }
      }
    }
  }
}

// ---- CSR build (both graphs in one pass; deg/fil [2N], rp [2(N+1)]) ----
__global__ void hist2_kernel(const int* __restrict__ trg0, const int* __restrict__ trg1,
                             int* __restrict__ deg, int E, int N) {
  int e = blockIdx.x * 256 + threadIdx.x;
  if (e < E) atomicAdd(&deg[trg0[e]], 1);
  else if (e < 2 * E) atomicAdd(&deg[N + trg1[e - E]], 1);
}

__global__ __launch_bounds__(1024) void scan_kernel(const int* __restrict__ degb,
                                                    int* __restrict__ rpb,
                                                    int* __restrict__ filb, int N) {
  const int* deg = degb + (long)blockIdx.x * N;
  int* row_ptr = rpb + (long)blockIdx.x * (N + 1);
  int* fil = filb + (long)blockIdx.x * N;
  __shared__ int sums[1024];
  int tid = threadIdx.x;
  int chunk = (N + 1023) >> 10;
  int start = tid * chunk;
  int end = start + chunk;
  if (start > N) start = N;
  if (end > N) end = N;
  int s = 0;
  for (int i = start; i < end; i++) s += deg[i];
  sums[tid] = s;
  __syncthreads();
  for (int off = 1; off < 1024; off <<= 1) {
    int add = (tid >= off) ? sums[tid - off] : 0;
    __syncthreads();
    sums[tid] += add;
    __syncthreads();
  }
  int run = (tid > 0) ? sums[tid - 1] : 0;
  for (int i = start; i < end; i++) {
    row_ptr[i] = run;
    fil[i] = run;
    run += deg[i];
  }
  if (tid == 0) row_ptr[N] = sums[1023];
}

__global__ void fill2_kernel(const int* __restrict__ src0, const int* __restrict__ trg0,
                             const int* __restrict__ src1, const int* __restrict__ trg1,
                             int* __restrict__ filb, int* __restrict__ colb, int E, int N) {
  int e = blockIdx.x * 256 + threadIdx.x;
  if (e < E) {
    int t = trg0[e];
    int pos = atomicAdd(&filb[t], 1);
    colb[pos] = src0[e];
  } else if (e < 2 * E) {
    int ee = e - E;
    int t = trg1[ee];
    int pos = atomicAdd(&filb[N + t], 1);
    colb[E + pos] = src1[ee];
  }
}

// ---------------------------------------------------------------------------
// GAT aggregation, fused single pass: out = (Σ_e ex_e · hp[src_e]) / (Σ_e ex_e).
// Round-6 structure: ONE wave per node (4 nodes per block). Lane c owns bytes
// [c*16,c*16+16) of the 1KB row (head h = c>>3). Edge srcs staged one-per-lane
// + __shfl broadcast; double-buffered 4-edge pipeline. blockIdx.y = type slot.
// mode 0: bf16 out[n*512 + o] = elu(sum)
// mode 1: float out[n*128 + o] = mean_h(sum)  (out base pre-offset per type)
// ---------------------------------------------------------------------------
__device__ __forceinline__ float exleaky(float v) {
  v = v > 0.f ? v : 0.2f * v;
  return __expf(v);
}

__global__ __launch_bounds__(256) void aggregate(AArg aa, int N, int mode) {
  const int ty = blockIdx.y;
  const bf16* __restrict__ hpb = aa.hp[ty];
  const float* __restrict__ svb = aa.sv[ty];
  const float* __restrict__ tvb = aa.tv[ty];
  const int* __restrict__ rp = aa.rp[ty];
  const int* __restrict__ colv = aa.col[ty];
  void* __restrict__ outp = aa.out[ty];
  const int wid = threadIdx.x >> 6;
  const int lane = threadIdx.x & 63;
  const int n = blockIdx.x * 4 + wid;
  if (n >= N) return;
  const int start = rp[n];
  const int deg = rp[n + 1] - start;
  const int h = lane >> 3;
  const float tvh = tvb[(long)n * 8 + h];
  const bf16* __restrict__ hpc = hpb + lane * 8;

  float acc[8] = {0.f, 0.f, 0.f, 0.f, 0.f, 0.f, 0.f, 0.f};
  float den = 1e-16f;

#define AG_LOAD(EB, V0, V1, V2, V3, Q0, Q1, Q2, Q3)                 \
  {                                                                 \
    int t0 = __shfl(mysrc, (EB) + 0), t1 = __shfl(mysrc, (EB) + 1); \
    int t2 = __shfl(mysrc, (EB) + 2), t3 = __shfl(mysrc, (EB) + 3); \
    V0 = *(const short8*)(hpc + (long)t0 * 512);                    \
    V1 = *(const short8*)(hpc + (long)t1 * 512);                    \
    V2 = *(const short8*)(hpc + (long)t2 * 512);                    \
    V3 = *(const short8*)(hpc + (long)t3 * 512);                    \
    Q0 = svb[(long)t0 * 8 + h];                                     \
    Q1 = svb[(long)t1 * 8 + h];                                     \
    Q2 = svb[(long)t2 * 8 + h];                                     \
    Q3 = svb[(long)t3 * 8 + h];                                     \
  }
#define AG_ACC(V0, V1, V2, V3, Q0, Q1, Q2, Q3)                      \
  {                                                                 \
    float a0 = exleaky(Q0 + tvh), a1 = exleaky(Q1 + tvh);           \
    float a2 = exleaky(Q2 + tvh), a3 = exleaky(Q3 + tvh);           \
    den += a0 + a1 + a2 + a3;                                       \
    _Pragma("unroll")                                               \
    for (int j = 0; j < 8; j++)                                     \
      acc[j] += a0 * bfbits2f(V0[j]) + a1 * bfbits2f(V1[j]) +       \
                a2 * bfbits2f(V2[j]) + a3 * bfbits2f(V3[j]);        \
  }

  for (int base = 0; base < deg; base += 64) {
    int cnt = deg - base;
    if (cnt > 64) cnt = 64;
    int mysrc = (lane < cnt) ? colv[start + base + lane] : 0;
    int nfull = cnt & ~3;
    if (nfull) {
      short8 v0, v1, v2, v3;
      float q0, q1, q2, q3;
      AG_LOAD(0, v0, v1, v2, v3, q0, q1, q2, q3);
      for (int e = 4; e < nfull; e += 4) {
        short8 w0 = v0, w1 = v1, w2 = v2, w3 = v3;
        float p0 = q0, p1 = q1, p2 = q2, p3 = q3;
        AG_LOAD(e, v0, v1, v2, v3, q0, q1, q2, q3);
        AG_ACC(w0, w1, w2, w3, p0, p1, p2, p3);
      }
      AG_ACC(v0, v1, v2, v3, q0, q1, q2, q3);
    }
    for (int e = nfull; e < cnt; e++) {
      int s0 = __shfl(mysrc, e);
      short8 v = *(const short8*)(hpc + (long)s0 * 512);
      float a = exleaky(svb[(long)s0 * 8 + h] + tvh);
      den += a;
#pragma unroll
      for (int j = 0; j < 8; j++) acc[j] += a * bfbits2f(v[j]);
    }
  }

  const float dinv = 1.f / den;
  if (mode == 0) {
    short8 o8;
#pragma unroll
    for (int j = 0; j < 8; j++) {
      float s = acc[j] * dinv;
      float ev = s > 0.f ? s : expm1f(s);
      o8[j] = f2bfbits(ev);
    }
    *(short8*)((bf16*)outp + (long)n * 512 + lane * 8) = o8;
  } else {
    float r[8];
#pragma unroll
    for (int j = 0; j < 8; j++) r[j] = acc[j] * dinv;
    // sum across the 8 lanes {q, q+8, ..., q+56} (q = lane&7): heads 0..7
#pragma unroll
    for (int m = 8; m <= 32; m <<= 1)
#pragma unroll
      for (int j = 0; j < 8; j++) r[j] += __shfl_xor(r[j], m);
    if (lane < 8) {
      float* o = (float*)outp + (long)n * 128 + lane * 8;
#pragma unroll
      for (int j = 0; j < 8; j++) o[j] = r[j] * 0.125f;
    }
  }
}

// favec[o] = trans1[0,:]·aw1[:,o] — 4 waves, each a 64-k partial, LDS combine.
__global__ __launch_bounds__(256) void favec_kernel(const bf16* __restrict__ trans1,
                                                    const void* __restrict__ aw1,
                                                    float* __restrict__ favec,
                                                    const int* __restrict__ flag) {
  const int f32 = flag[0];
  __shared__ float part[4][64];
  const int o = threadIdx.x & 63;
  const int wv = threadIdx.x >> 6;
  float acc = 0.f;
#pragma unroll
  for (int kk = 0; kk < 64; kk++) {
    int k = wv * 64 + kk;
    acc += bf2f(trans1[k]) * ldin(aw1, (long)k * 64 + o, f32);
  }
  part[wv][o] = acc;
  __syncthreads();
  if (threadIdx.x < 64) favec[o] = part[0][o] + part[1][o] + part[2][o] + part[3][o];
}

// ---------------------------------------------------------------------------
// Semantic attention + FC + log_softmax. 16 nodes per 256-thread block.
// ---------------------------------------------------------------------------
#define FN 16
__global__ __launch_bounds__(256) void final_kernel(const float* __restrict__ ta,
                                                    const float* __restrict__ favec,
                                                    const void* __restrict__ aw2,
                                                    const void* __restrict__ am,
                                                    const void* __restrict__ fcw,
                                                    const void* __restrict__ fcb,
                                                    void* __restrict__ out, int N,
                                                    const int* __restrict__ flag) {
  const int f32 = flag[0];
  __shared__ float s_w[64 * 64];
  __shared__ float s_fc[384];
  __shared__ float s_misc[130];     // [0:64) favec, [64:128) am, [128:130) fcb
  __shared__ float s_ta[FN * 128];  // [ni][k][r] : ta0/ta1 interleaved
  const int tid = threadIdx.x;
  const int n0 = blockIdx.x * FN;
  for (int i = tid; i < 4096; i += 256) s_w[i] = ldin(aw2, i, f32);
  for (int i = tid; i < 384; i += 256) s_fc[i] = ldin(fcw, i, f32);
  if (tid < 64) s_misc[tid] = favec[tid];
  else if (tid < 128) s_misc[tid] = ldin(am, tid - 64, f32);
  else if (tid < 130) s_misc[tid] = ldin(fcb, tid - 128, f32);
  for (int idx = tid; idx < FN * 128; idx += 256) {
    int ni = idx >> 7;
    int j = idx & 127;
    int k = j >> 1, r = j & 1;
    int n = n0 + ni;
    s_ta[idx] = (n < N) ? ta[(long)n * 128 + r * 64 + k] : 0.f;
  }
  __syncthreads();
  const int o = tid & 63;
  const int wv = tid >> 6;
#pragma unroll
  for (int ni4 = 0; ni4 < 4; ni4++) {
    const int ni = wv * 4 + ni4;
    const int n = n0 + ni;
    if (n >= N) continue;
    const float* tb = &s_ta[ni * 128];
    float acc0 = s_misc[o], acc1 = acc0;
#pragma unroll 8
    for (int k = 0; k < 64; k++) {
      float2 t2 = *(const float2*)(tb + k * 2);  // broadcast (same addr)
      float w = s_w[k * 64 + o];
      acc0 += t2.x * w;
      acc1 += t2.y * w;
    }
    float ta0 = tb[o * 2];
    float ta1 = tb[o * 2 + 1];
    float amv = s_misc[64 + o];
    float p0 = tanhf(acc0) * amv;
    float p1 = tanhf(acc1) * amv;
#pragma unroll
    for (int off = 32; off > 0; off >>= 1) {
      p0 += __shfl_xor(p0, off);
      p1 += __shfl_xor(p1, off);
    }
    float mx = fmaxf(p0, p1);
    float e0 = __expf(p0 - mx), e1 = __expf(p1 - mx);
    float b0 = e0 / (e0 + e1), b1 = e1 / (e0 + e1);
    float fus = b0 * ta0 + b1 * ta1;
    float l0 = ta0 * s_fc[o * 2 + 0] + ta1 * s_fc[(64 + o) * 2 + 0] + fus * s_fc[(128 + o) * 2 + 0];
    float l1 = ta0 * s_fc[o * 2 + 1] + ta1 * s_fc[(64 + o) * 2 + 1] + fus * s_fc[(128 + o) * 2 + 1];
#pragma unroll
    for (int off = 32; off > 0; off >>= 1) {
      l0 += __shfl_xor(l0, off);
      l1 += __shfl_xor(l1, off);
    }
    if (o == 0) {
      l0 += s_misc[128];
      l1 += s_misc[129];
      float m2 = fmaxf(l0, l1);
      float lse = m2 + logf(__expf(l0 - m2) + __expf(l1 - m2));
      if (f32) {
        ((float*)out)[n * 2 + 0] = l0 - lse;
        ((float*)out)[n * 2 + 1] = l1 - lse;
      } else {
        ((bf16*)out)[n * 2 + 0] = __float2bfloat16(l0 - lse);
        ((bf16*)out)[n * 2 + 1] = __float2bfloat16(l1 - lse);
      }
    }
  }
}

extern "C" void kernel_launch(void* const* d_in, const int* in_sizes, int n_in,
                              void* d_out, int out_size, void* d_ws, size_t ws_size,
                              hipStream_t stream) {
  constexpr int N = 20000, E = 320000, H = 8, F0 = 128, FU = 256, FO = 64;
  const void* hemb[2] = {d_in[0], d_in[1]};
  const void* W[2] = {d_in[2], d_in[3]};
  const void* gw[2][2] = {{d_in[4], d_in[7]}, {d_in[10], d_in[13]}};
  const void* gasrc[2][2] = {{d_in[5], d_in[8]}, {d_in[11], d_in[14]}};
  const void* gatrg[2][2] = {{d_in[6], d_in[9]}, {d_in[12], d_in[15]}};
  const void* aw1 = d_in[16];
  const void* aw2 = d_in[17];
  const void* am = d_in[18];
  const void* fcw = d_in[19];
  const void* fcb = d_in[20];
  const int* edge[2] = {(const int*)d_in[21], (const int*)d_in[22]};

  // Batched (grid.z=2) path needs doubled trans/hp/xbuf/sv/tv.
  const size_t szTrans = (size_t)N * FU * 2;   // bf16 bytes
  const size_t szHp = (size_t)N * 512 * 2;
  const size_t szSv = (size_t)N * 8 * 4;
  size_t need = 0;
  auto addsz = [&](size_t b) { need += (b + 255) & ~(size_t)255; };
  addsz(4);
  addsz(szTrans * 2); addsz(szHp * 2); addsz(szHp * 2);
  addsz(szSv * 2); addsz(szSv * 2);
  addsz((size_t)N * 128 * 4); addsz(256);
  addsz((size_t)2 * N * 4); addsz((size_t)2 * (N + 1) * 4);
  addsz((size_t)2 * N * 4); addsz((size_t)2 * E * 4);
  const bool batched = (ws_size >= need + 4096);
  const int TB = batched ? 2 : 1;

  char* p = (char*)d_ws;
  auto alloc = [&](size_t bytes) -> void* {
    void* r = (void*)p;
    p += (bytes + 255) & ~(size_t)255;
    return r;
  };
  int* flag = (int*)alloc(4);
  bf16* trans = (bf16*)alloc(szTrans * TB);
  bf16* hp = (bf16*)alloc(szHp * TB);
  bf16* xbuf = (bf16*)alloc(szHp * TB);
  float* sv = (float*)alloc(szSv * TB);
  float* tv = (float*)alloc(szSv * TB);
  float* ta = (float*)alloc((size_t)N * 128 * 4);
  float* favec = (float*)alloc(256);
  int* degb = (int*)alloc((size_t)2 * N * 4);
  int* rpb = (int*)alloc((size_t)2 * (N + 1) * 4);
  int* filb = (int*)alloc((size_t)2 * N * 4);
  int* colb = (int*)alloc((size_t)2 * E * 4);

  detect_kernel<<<1, 64, 0, stream>>>(hemb[0], flag);

  // CSR build for both graphs in one pass
  hipMemsetAsync(degb, 0, (size_t)2 * N * 4, stream);
  hist2_kernel<<<(2 * E + 255) / 256, 256, 0, stream>>>(edge[0] + E, edge[1] + E, degb, E, N);
  scan_kernel<<<2, 1024, 0, stream>>>(degb, rpb, filb, N);
  fill2_kernel<<<(2 * E + 255) / 256, 256, 0, stream>>>(edge[0], edge[0] + E,
                                                        edge[1], edge[1] + E, filb, colb, E, N);

  const int gmx = (N + GBM - 1) / GBM;  // 157
  const int npass = batched ? 1 : 2;
  const int TC = batched ? 2 : 1;

  // per-slot workspace pointers (slot i covers type t; buffer index b)
  auto transP = [&](int b) { return trans + (size_t)b * N * FU; };
  auto hpP = [&](int b) { return hp + (size_t)b * N * 512; };
  auto xbufP = [&](int b) { return xbuf + (size_t)b * N * 512; };
  auto svP = [&](int b) { return sv + (size_t)b * N * 8; };
  auto tvP = [&](int b) { return tv + (size_t)b * N * 8; };

  for (int pass = 0; pass < npass; pass++) {
    int types[2] = {batched ? 0 : pass, batched ? 1 : pass};
    int bufs[2] = {batched ? 0 : 0, batched ? 1 : 0};

    GArg g0{};
    for (int i = 0; i < TC; i++) {
      int t = types[i], b = bufs[i];
      g0.A[i] = hemb[t]; g0.B[i] = W[t]; g0.C[i] = transP(b);
      g0.sa[i] = nullptr; g0.sb[i] = nullptr; g0.sv[i] = nullptr; g0.tv[i] = nullptr;
    }
    gemm_mfma<<<dim3(gmx, FU / GBN, TC), 256, 0, stream>>>(g0, 1, 0, N, F0, FU, flag);

    GArg g1{};
    for (int i = 0; i < TC; i++) {
      int t = types[i], b = bufs[i];
      g1.A[i] = transP(b); g1.B[i] = gw[t][0]; g1.C[i] = hpP(b);
      g1.sa[i] = gasrc[t][0]; g1.sb[i] = gatrg[t][0]; g1.sv[i] = svP(b); g1.tv[i] = tvP(b);
    }
    gemm_mfma<<<dim3(gmx, (H * FO) / GBN, TC), 256, 0, stream>>>(g1, 0, 1, N, FU, H * FO, flag);

    AArg a0{};
    for (int i = 0; i < TC; i++) {
      int t = types[i], b = bufs[i];
      a0.hp[i] = hpP(b); a0.sv[i] = svP(b); a0.tv[i] = tvP(b);
      a0.rp[i] = rpb + (size_t)t * (N + 1); a0.col[i] = colb + (size_t)t * E;
      a0.out[i] = xbufP(b);
    }
    aggregate<<<dim3((N + 3) / 4, TC), 256, 0, stream>>>(a0, N, 0);

    GArg g2{};
    for (int i = 0; i < TC; i++) {
      int t = types[i], b = bufs[i];
      g2.A[i] = xbufP(b); g2.B[i] = gw[t][1]; g2.C[i] = hpP(b);
      g2.sa[i] = gasrc[t][1]; g2.sb[i] = gatrg[t][1]; g2.sv[i] = svP(b); g2.tv[i] = tvP(b);
    }
    gemm_mfma<<<dim3(gmx, (H * FO) / GBN, TC), 256, 0, stream>>>(g2, 0, 1, N, H * FO, H * FO, flag);

    AArg a1{};
    for (int i = 0; i < TC; i++) {
      int t = types[i], b = bufs[i];
      a1.hp[i] = hpP(b); a1.sv[i] = svP(b); a1.tv[i] = tvP(b);
      a1.rp[i] = rpb + (size_t)t * (N + 1); a1.col[i] = colb + (size_t)t * E;
      a1.out[i] = ta + (size_t)t * FO;
    }
    aggregate<<<dim3((N + 3) / 4, TC), 256, 0, stream>>>(a1, N, 1);
  }

  // feature = trans1[0,:] (type-1's transformed embedding, row 0)
  const bf16* trans1 = batched ? transP(1) : transP(0);
  favec_kernel<<<1, 256, 0, stream>>>(trans1, aw1, favec, flag);
  final_kernel<<<(N + FN - 1) / FN, 256, 0, stream>>>(ta, favec, aw2, am, fcw, fcb, d_out, N, flag);
}